// Round 2
// baseline (2155.175 us; speedup 1.0000x reference)
//
#include <hip/hip_runtime.h>
#include <math.h>

#define NB 128
#define SEQ 17
#define DM 192
#define DI 384
#define DEPTH 12
#define ROW (SEQ*DM)     // 3264
#define XROW (SEQ*DI)    // 6528

struct MambaW {
  const float* norm_w;
  const float* in_proj;
  const float* conv_w;
  const float* conv_b;
  const float* x_proj;
  const float* dt_w;
  const float* dt_b;
  const float* A_log;
  const float* D;
  const float* out_proj;
};

__device__ __forceinline__ float dot4(float4 a, float4 b) {
  return a.x*b.x + a.y*b.y + a.z*b.z + a.w*b.w;
}

// ---------------------------------------------------------------------------
// Patch embed + layer-0 RMSNorm. grid 256 = (bg 0..15)x(p 0..15), block 192.
// Writes res (= embed output) and hbuf (= rmsnorm(res)*norm_w[0]).
// ---------------------------------------------------------------------------
__global__ __launch_bounds__(192, 1) void embed_kernel(
    const float* __restrict__ x, const float* __restrict__ w,
    const float* __restrict__ bias, const float* __restrict__ tok,
    const float* __restrict__ pos, const float* __restrict__ nw,
    float* __restrict__ res, float* __restrict__ hbuf, int is_f)
{
  const int t = threadIdx.x;
  const int p = blockIdx.x & 15;
  const int bg = blockIdx.x >> 4;
  __shared__ alignas(16) float xs[8*1792];
  __shared__ float lds_sq[9*192];
  __shared__ float lds_pt[9*16];
  __shared__ float lds_sc[9];

  for (int idx = t; idx < 8*1792; idx += 192) {
    int bb = idx / 1792;
    int r = idx - bb*1792;
    int b = bg*8 + bb;
    if (!is_f) {
      int c = r / 224;
      int rr = r - c*224;
      xs[idx] = x[((size_t)(b*8 + c)*224 + p*14)*16 + rr];
    } else {
      xs[idx] = x[((size_t)b*1792 + r)*16 + p];
    }
  }
  __syncthreads();

  float acc[8];
#pragma unroll
  for (int i = 0; i < 8; ++i) acc[i] = 0.f;
  const float4* wr = (const float4*)w + t*448;
  const float4* xv = (const float4*)xs;
  for (int k4 = 0; k4 < 448; ++k4) {
    float4 w4 = wr[k4];
#pragma unroll
    for (int bb = 0; bb < 8; ++bb) acc[bb] += dot4(xv[bb*448 + k4], w4);
  }
  float add = bias[t] + pos[p*DM + t];
  float v[8];
#pragma unroll
  for (int bb = 0; bb < 8; ++bb) {
    v[bb] = acc[bb] + add;
    lds_sq[bb*192 + t] = v[bb]*v[bb];
  }
  float v16 = tok[t] + pos[16*DM + t];
  lds_sq[8*192 + t] = v16*v16;
  __syncthreads();
  if (t < 144) {
    int r = t >> 4, j = t & 15;
    float s = 0.f;
#pragma unroll
    for (int k = 0; k < 12; ++k) { float e = lds_sq[r*192 + j + 16*k]; s += e*e*0.f + e; }
    lds_pt[t] = s;
  }
  __syncthreads();
  if (t < 9) {
    float s = 0.f;
#pragma unroll
    for (int j = 0; j < 16; ++j) s += lds_pt[t*16 + j];
    lds_sc[t] = rsqrtf(s*(1.0f/192.0f) + 1e-5f);
  }
  __syncthreads();
  float nwt = nw[t];
#pragma unroll
  for (int bb = 0; bb < 8; ++bb) {
    size_t base = (size_t)(bg*8 + bb)*ROW;
    res[base + p*DM + t]  = v[bb];
    hbuf[base + p*DM + t] = v[bb]*lds_sc[bb]*nwt;
  }
  if (p == 0) {
    float s16 = lds_sc[8];
#pragma unroll
    for (int bb = 0; bb < 8; ++bb) {
      size_t base = (size_t)(bg*8 + bb)*ROW;
      res[base + 16*DM + t]  = v16;
      hbuf[base + 16*DM + t] = v16*s16*nwt;
    }
  }
}

// ---------------------------------------------------------------------------
// in_proj + causal conv + SiLU. grid (3, 256)= (col-chunk, sb), block 256.
// h read from hbuf with wave-uniform indices -> scalar loads (s_load),
// weights stream per-thread via vector loads. 12 waves/CU.
// ---------------------------------------------------------------------------
__global__ __launch_bounds__(256, 3) void inproj_kernel(
    const float* __restrict__ hbuf, MambaW wt, MambaW wf,
    float* __restrict__ xxg, float* __restrict__ zg, int layer)
{
  const int t = threadIdx.x;
  const int chunk = blockIdx.x;
  const int sb = blockIdx.y;
  const MambaW W = (sb >= NB) ? wf : wt;
  const int o = chunk*256 + t;

  const float4* h4 = (const float4*)(hbuf + (size_t)sb*ROW);  // uniform reads
  const float4* wr = (const float4*)(W.in_proj + (size_t)layer*768*DM) + o*48;
  float acc[SEQ];
#pragma unroll
  for (int l = 0; l < SEQ; ++l) acc[l] = 0.f;
  for (int k4 = 0; k4 < 48; ++k4) {
    float4 w4 = wr[k4];
#pragma unroll
    for (int l = 0; l < SEQ; ++l) acc[l] += dot4(h4[l*48 + k4], w4);
  }
  size_t xbase = (size_t)sb*XROW;
  if (o < DI) {
    const float4 cw = ((const float4*)(W.conv_w + (size_t)layer*DI*4))[o];
    const float cb = W.conv_b[layer*DI + o];
#pragma unroll
    for (int l = 0; l < SEQ; ++l) {
      float vv = cb + acc[l]*cw.w;
      if (l >= 1) vv += acc[l-1]*cw.z;
      if (l >= 2) vv += acc[l-2]*cw.y;
      if (l >= 3) vv += acc[l-3]*cw.x;
      vv = vv / (1.f + __expf(-vv));
      xxg[xbase + l*DI + o] = vv;
    }
  } else {
    int c = o - DI;
#pragma unroll
    for (int l = 0; l < SEQ; ++l) zg[xbase + l*DI + c] = acc[l];
  }
}

// ---------------------------------------------------------------------------
// x_proj + dt + selective scan + gate + out_proj + (residual+RMSNorm epilogue
// for the NEXT layer). grid 256 (sb), block 768 -> 12 waves/CU.
// ---------------------------------------------------------------------------
__global__ __launch_bounds__(768, 3) void scan_kernel(
    const float* __restrict__ xxg, const float* __restrict__ zg,
    float* __restrict__ res, float* __restrict__ hbuf, float* __restrict__ xbuf,
    MambaW wt, MambaW wf, int layer, int last)
{
  const int t = threadIdx.x;
  const int sb = blockIdx.x;
  const MambaW W = (sb >= NB) ? wf : wt;
  __shared__ alignas(16) float lds_xx[SEQ*388];   // silu(conv(xx)); later gated y
  __shared__ alignas(16) float lds_dbl[SEQ*44];
  __shared__ float lds_res[SEQ*194];
  __shared__ float lds_pt[SEQ*16];
  __shared__ float lds_sc[SEQ];

  const size_t xbase = (size_t)sb*XROW;
  const size_t rbase = (size_t)sb*ROW;

  for (int idx = t; idx < XROW; idx += 768) {
    int l = idx / DI, c = idx - l*DI;
    lds_xx[l*388 + c] = xxg[xbase + idx];
  }
  __syncthreads();

  // x_proj: 748 outputs (l, j<44)
  if (t < 748) {
    int l = t / 44, j = t - l*44;
    const float4* wr = (const float4*)(W.x_proj + (size_t)layer*44*DI + (size_t)j*DI);
    const float4* xr = (const float4*)lds_xx + l*97;
    float a = 0.f;
    for (int k4 = 0; k4 < 96; ++k4) a += dot4(xr[k4], wr[k4]);
    lds_dbl[t] = a;
  }
  __syncthreads();

  // dt + scan + gate, channel c = t (threads >= 384 idle here)
  if (t < DI) {
    const int c = t;
    const float* dwr = W.dt_w + (size_t)layer*DI*12 + c*12;
    float w0[12];
#pragma unroll
    for (int r = 0; r < 12; ++r) w0[r] = dwr[r];
    const float dtb = W.dt_b[layer*DI + c];
    const float4* alr = (const float4*)(W.A_log + (size_t)layer*DI*16) + c*4;
    float Av[16];
#pragma unroll
    for (int q = 0; q < 4; ++q) {
      float4 a4 = alr[q];
      Av[q*4+0] = -__expf(a4.x); Av[q*4+1] = -__expf(a4.y);
      Av[q*4+2] = -__expf(a4.z); Av[q*4+3] = -__expf(a4.w);
    }
    const float Dp = W.D[layer*DI + c];
    float hst[16];
#pragma unroll
    for (int n = 0; n < 16; ++n) hst[n] = 0.f;
    for (int l = 0; l < SEQ; ++l) {
      float a = dtb;
#pragma unroll
      for (int r = 0; r < 12; ++r) a += lds_dbl[l*44 + r]*w0[r];
      float dt = (a > 20.f) ? a : log1pf(__expf(a));
      float xv = lds_xx[l*388 + c];
      const float4* dbv = (const float4*)(lds_dbl + l*44 + 12);
      float4 Bq[4], Cq[4];
      Bq[0]=dbv[0]; Bq[1]=dbv[1]; Bq[2]=dbv[2]; Bq[3]=dbv[3];
      Cq[0]=dbv[4]; Cq[1]=dbv[5]; Cq[2]=dbv[6]; Cq[3]=dbv[7];
      const float* Bs = (const float*)Bq;
      const float* Cs = (const float*)Cq;
      float y = 0.f;
      float dbx = dt * xv;
#pragma unroll
      for (int n = 0; n < 16; ++n) {
        float dA = __expf(dt * Av[n]);
        float hn = dA*hst[n] + dbx*Bs[n];
        hst[n] = hn;
        y += hn*Cs[n];
      }
      y += Dp * xv;
      float zv = zg[xbase + l*DI + c];
      y *= zv / (1.f + __expf(-zv));
      lds_xx[l*388 + c] = y;
    }
  }
  __syncthreads();

  // out_proj: thread (lg = t/192 wave-uniform, d = t%192); rows l = lg+4q (+16 for lg==0)
  const int lg = t / 192;
  const int d = t - lg*192;
  {
    const float4* wr = (const float4*)(W.out_proj + (size_t)layer*DM*DI) + d*96;
    const float4* yv = (const float4*)lds_xx;
    float acc[5];
#pragma unroll
    for (int q = 0; q < 5; ++q) acc[q] = 0.f;
    for (int k4 = 0; k4 < 96; ++k4) {
      float4 w4 = wr[k4];
#pragma unroll
      for (int q = 0; q < 4; ++q) acc[q] += dot4(yv[(lg + 4*q)*97 + k4], w4);
      if (lg == 0) acc[4] += dot4(yv[16*97 + k4], w4);
    }
    if (!last) {
#pragma unroll
      for (int q = 0; q < 4; ++q) {
        int l = lg + 4*q;
        float vv = res[rbase + l*DM + d] + acc[q];
        res[rbase + l*DM + d] = vv;
        lds_res[l*194 + d] = vv;
      }
      if (lg == 0) {
        float vv = res[rbase + 16*DM + d] + acc[4];
        res[rbase + 16*DM + d] = vv;
        lds_res[16*194 + d] = vv;
      }
    } else {
#pragma unroll
      for (int q = 0; q < 4; ++q) xbuf[rbase + (lg + 4*q)*DM + d] = acc[q];
      if (lg == 0) xbuf[rbase + 16*DM + d] = acc[4];
    }
  }
  __syncthreads();

  if (!last) {
    if (t < 272) {
      int l = t >> 4, j = t & 15;
      float s = 0.f;
#pragma unroll
      for (int k = 0; k < 12; ++k) { float e = lds_res[l*194 + j + 16*k]; s += e*e; }
      lds_pt[t] = s;
    }
    __syncthreads();
    if (t < SEQ) {
      float s = 0.f;
#pragma unroll
      for (int j = 0; j < 16; ++j) s += lds_pt[t*16 + j];
      lds_sc[t] = rsqrtf(s*(1.0f/192.0f) + 1e-5f);
    }
    __syncthreads();
    const float* nw = W.norm_w + (size_t)(layer + 1)*DM;
    for (int idx = t; idx < ROW; idx += 768) {
      int l = idx / DM, d2 = idx - l*DM;
      hbuf[rbase + idx] = lds_res[l*194 + d2]*lds_sc[l]*nw[d2];
    }
  }
}

// ---------------------------------------------------------------------------
// Both cross-attentions + heads (query row 16 only). grid 128, block 256.
// ---------------------------------------------------------------------------
__global__ __launch_bounds__(256, 1) void attn_head_kernel(
    const float* __restrict__ xbuf,
    const float* __restrict__ w1, const float* __restrict__ b1,
    const float* __restrict__ w2, const float* __restrict__ b2,
    const float* __restrict__ c1w, const float* __restrict__ c1b,
    const float* __restrict__ c2w, const float* __restrict__ c2b,
    const float* __restrict__ p1w, const float* __restrict__ p1b,
    const float* __restrict__ p2w, const float* __restrict__ p2b,
    float* __restrict__ out)
{
  const int t = threadIdx.x;
  const int b = blockIdx.x;
  __shared__ alignas(16) float lds_f[ROW];
  __shared__ alignas(16) float lds_k[ROW];
  __shared__ alignas(16) float lds_v[ROW];
  __shared__ alignas(16) float lds_trow[DM];
  __shared__ alignas(16) float lds_q[DM];
  __shared__ alignas(16) float lds_o[DM];
  __shared__ alignas(16) float lds_t1[DM];
  __shared__ alignas(16) float lds_feat[DM];
  __shared__ alignas(16) float lds_hc[512];
  __shared__ alignas(16) float lds_hp[512];

  const float* fp = xbuf + (size_t)(NB + b)*ROW;
  const float* tp = xbuf + (size_t)b*ROW;
  for (int idx = t; idx < ROW; idx += 256) lds_f[idx] = fp[idx];
  if (t < DM) lds_trow[t] = tp[16*DM + t];
  __syncthreads();

  for (int pass = 0; pass < 2; ++pass) {
    const float* wa = pass ? w2 : w1;
    const float* ba = pass ? b2 : b1;
    if (t < DM) {
      for (int m = 1; m <= 2; ++m) {
        const float4* wr = (const float4*)(wa + m*DM*DM) + t*48;
        float acc[17];
#pragma unroll
        for (int l = 0; l < 17; ++l) acc[l] = 0.f;
        for (int k4 = 0; k4 < 48; ++k4) {
          float4 w4 = wr[k4];
#pragma unroll
          for (int l = 0; l < 17; ++l)
            acc[l] += dot4(((const float4*)lds_f)[l*48 + k4], w4);
        }
        float bv = ba[m*DM + t];
        float* dst = (m == 1) ? lds_k : lds_v;
#pragma unroll
        for (int l = 0; l < 17; ++l) dst[l*DM + t] = acc[l] + bv;
      }
      {
        const float* qsrc = pass ? lds_t1 : lds_trow;
        const float4* wr = (const float4*)wa + t*48;
        const float4* a4 = (const float4*)qsrc;
        float acc = ba[t];
        for (int k4 = 0; k4 < 48; ++k4) acc += dot4(a4[k4], wr[k4]);
        lds_q[t] = acc;
      }
    }
    __syncthreads();
    if (t < DM) {
      int h = t / 24;
      float sc[17];
      float mx = -1e30f;
#pragma unroll
      for (int lk = 0; lk < 17; ++lk) {
        float s_ = 0.f;
#pragma unroll
        for (int j = 0; j < 24; ++j)
          s_ += lds_q[h*24 + j] * lds_k[lk*DM + h*24 + j];
        s_ *= 0.20412414523193154f;
        sc[lk] = s_;
        mx = fmaxf(mx, s_);
      }
      float den = 0.f;
#pragma unroll
      for (int lk = 0; lk < 17; ++lk) { float e = __expf(sc[lk] - mx); sc[lk] = e; den += e; }
      float inv = 1.f / den;
      float o = 0.f;
#pragma unroll
      for (int lk = 0; lk < 17; ++lk) o += sc[lk] * lds_v[lk*DM + t];
      lds_o[t] = o * inv;
    }
    __syncthreads();
    if (t < DM) {
      const float4* wr = (const float4*)(wa + 3*DM*DM) + t*48;
      const float4* a4 = (const float4*)lds_o;
      float acc = ba[3*DM + t];
      for (int k4 = 0; k4 < 48; ++k4) acc += dot4(a4[k4], wr[k4]);
      if (pass == 0) lds_t1[t] = acc;
      else lds_feat[t] = acc + lds_trow[t];
    }
    __syncthreads();
  }

  for (int u = t; u < 512; u += 256) {
    const float4* wc = (const float4*)c1w + u*48;
    const float4* wp = (const float4*)p1w + u*48;
    const float4* fv = (const float4*)lds_feat;
    float a1 = c1b[u], a2 = p1b[u];
    for (int k4 = 0; k4 < 48; ++k4) {
      float4 f4 = fv[k4];
      a1 += dot4(f4, wc[k4]);
      a2 += dot4(f4, wp[k4]);
    }
    lds_hc[u] = fmaxf(a1, 0.f);
    lds_hp[u] = fmaxf(a2, 0.f);
  }
  __syncthreads();
  if (t < 10) {
    const float4* wr = (const float4*)c2w + t*128;
    float acc = c2b[t];
    for (int k4 = 0; k4 < 128; ++k4) acc += dot4(((const float4*)lds_hc)[k4], wr[k4]);
    out[b*10 + t] = acc;
  }
  if (t >= 64 && t < 67) {
    int j = t - 64;
    const float4* wr = (const float4*)p2w + j*128;
    float acc = p2b[j];
    for (int k4 = 0; k4 < 128; ++k4) acc += dot4(((const float4*)lds_hp)[k4], wr[k4]);
    out[1280 + b*3 + j] = acc;
  }
}

extern "C" void kernel_launch(void* const* d_in, const int* in_sizes, int n_in,
                              void* d_out, int out_size, void* d_ws, size_t ws_size,
                              hipStream_t stream)
{
  (void)in_sizes; (void)n_in; (void)out_size; (void)ws_size;
  const float* x    = (const float*)d_in[0];
  const float* tpw  = (const float*)d_in[1];
  const float* tpb  = (const float*)d_in[2];
  const float* fpw  = (const float*)d_in[3];
  const float* fpb  = (const float*)d_in[4];
  const float* ttok = (const float*)d_in[5];
  const float* ftok = (const float*)d_in[6];
  const float* tpos = (const float*)d_in[7];
  const float* fpos = (const float*)d_in[8];
  MambaW wt { (const float*)d_in[9],  (const float*)d_in[10], (const float*)d_in[11],
              (const float*)d_in[12], (const float*)d_in[13], (const float*)d_in[14],
              (const float*)d_in[15], (const float*)d_in[16], (const float*)d_in[17],
              (const float*)d_in[18] };
  MambaW wf { (const float*)d_in[19], (const float*)d_in[20], (const float*)d_in[21],
              (const float*)d_in[22], (const float*)d_in[23], (const float*)d_in[24],
              (const float*)d_in[25], (const float*)d_in[26], (const float*)d_in[27],
              (const float*)d_in[28] };
  const float* attw  = (const float*)d_in[29];
  const float* attb  = (const float*)d_in[30];
  const float* attw2 = (const float*)d_in[31];
  const float* attb2 = (const float*)d_in[32];
  const float* c1w = (const float*)d_in[33];
  const float* c1b = (const float*)d_in[34];
  const float* c2w = (const float*)d_in[35];
  const float* c2b = (const float*)d_in[36];
  const float* p1w = (const float*)d_in[37];
  const float* p1b = (const float*)d_in[38];
  const float* p2w = (const float*)d_in[39];
  const float* p2b = (const float*)d_in[40];

  float* ws = (float*)d_ws;
  const size_t ROWN = (size_t)2*NB*ROW;   // 835584
  const size_t XROWN = (size_t)2*NB*XROW; // 1671168
  float* res  = ws;
  float* hbuf = ws + ROWN;
  float* xxg  = ws + 2*ROWN;
  float* zg   = xxg + XROWN;
  float* xbuf = zg + XROWN;

  embed_kernel<<<256, 192, 0, stream>>>(x, tpw, tpb, ttok, tpos, wt.norm_w,
                                        res, hbuf, 0);
  embed_kernel<<<256, 192, 0, stream>>>(x, fpw, fpb, ftok, fpos, wf.norm_w,
                                        res + (size_t)NB*ROW, hbuf + (size_t)NB*ROW, 1);
  for (int i = 0; i < DEPTH; ++i) {
    inproj_kernel<<<dim3(3, 256), 256, 0, stream>>>(hbuf, wt, wf, xxg, zg, i);
    scan_kernel<<<256, 768, 0, stream>>>(xxg, zg, res, hbuf, xbuf, wt, wf, i,
                                         (i == DEPTH-1) ? 1 : 0);
  }
  attn_head_kernel<<<128, 256, 0, stream>>>(xbuf, attw, attb, attw2, attb2,
      c1w, c1b, c2w, c2b, p1w, p1b, p2w, p2b, (float*)d_out);
}

// Round 3
// 1880.818 us; speedup vs baseline: 1.1459x; 1.1459x over previous
//
#include <hip/hip_runtime.h>
#include <math.h>

#define NB 128
#define SEQ 17
#define DM 192
#define DI 384
#define DEPTH 12
#define ROW (SEQ*DM)       // 3264
#define NROWS 4352         // 2*NB*SEQ
#define N192 (NROWS*DM)    // 835584

struct MambaW {
  const float* norm_w;
  const float* in_proj;
  const float* conv_w;
  const float* conv_b;
  const float* x_proj;
  const float* dt_w;
  const float* dt_b;
  const float* A_log;
  const float* D;
  const float* out_proj;
};

__device__ __forceinline__ float dot4(float4 a, float4 b) {
  return a.x*b.x + a.y*b.y + a.z*b.z + a.w*b.w;
}

// ---------------------------------------------------------------------------
// Tiled fp32 GEMM: C[n][m] = sum_k A[n][k]*B[m][k]  (B row-major in k).
// Tile: 128 rows (n) x MT=16*MR cols (m), K-tile 32, 256 threads, micro 8xMR.
// MODE 0: layer GEMM — B = (ntile<17 ? Bt : Bf), plain store (+kz K-split).
// MODE 1: attention K/V GEMM — m in [0,768) maps to {w1,w2}x{K,V}x96-half,
//         bias added on store.
// ---------------------------------------------------------------------------
template<int MR, int MODE>
__global__ __launch_bounds__(256, 3) void gemm_kernel(
    const float* __restrict__ A, int lda, int ktot,
    const float* __restrict__ Bt, const float* __restrict__ Bf, int ldb,
    const float* __restrict__ bias1, const float* __restrict__ bias2,
    float* __restrict__ C, int ldc, long ckstride)
{
  constexpr int MT = 16*MR;
  const int t  = threadIdx.x;
  const int mt = blockIdx.x, nt = blockIdx.y, kz = blockIdx.z;
  __shared__ float As[32][132];
  __shared__ float Bs[32][MT+4];

  const float* Bp;
  const float* bp = nullptr;
  if (MODE == 0) {
    Bp = ((nt < 17) ? Bt : Bf) + (size_t)(mt*MT)*ldb + kz*ktot;
  } else {
    int pass = mt >> 2, kv = (mt >> 1) & 1, half = mt & 1;
    Bp = (pass ? Bf : Bt) + (size_t)(1+kv)*DM*DM + (size_t)(half*96)*ldb;
    bp = (pass ? bias2 : bias1) + (1+kv)*DM + half*96;
  }
  const float* Ap = A + (size_t)(nt*128)*lda + kz*ktot;

  const int tn = t & 15, tm = t >> 4;
  float acc[8][MR];
#pragma unroll
  for (int i = 0; i < 8; ++i)
#pragma unroll
    for (int j = 0; j < MR; ++j) acc[i][j] = 0.f;

  const int srow = t >> 1;          // staging row (0..127)
  const int skl  = (t & 1) * 16;    // staging k-local base

  for (int kt = 0; kt < ktot; kt += 32) {
    __syncthreads();
    {
      const float* ar = Ap + (size_t)srow*lda + kt + skl;
      float4 v0 = *(const float4*)(ar + 0);
      float4 v1 = *(const float4*)(ar + 4);
      float4 v2 = *(const float4*)(ar + 8);
      float4 v3 = *(const float4*)(ar + 12);
      As[skl+ 0][srow]=v0.x; As[skl+ 1][srow]=v0.y; As[skl+ 2][srow]=v0.z; As[skl+ 3][srow]=v0.w;
      As[skl+ 4][srow]=v1.x; As[skl+ 5][srow]=v1.y; As[skl+ 6][srow]=v1.z; As[skl+ 7][srow]=v1.w;
      As[skl+ 8][srow]=v2.x; As[skl+ 9][srow]=v2.y; As[skl+10][srow]=v2.z; As[skl+11][srow]=v2.w;
      As[skl+12][srow]=v3.x; As[skl+13][srow]=v3.y; As[skl+14][srow]=v3.z; As[skl+15][srow]=v3.w;
    }
    if (MR == 8 || srow < MT) {
      const float* br = Bp + (size_t)srow*ldb + kt + skl;
      float4 v0 = *(const float4*)(br + 0);
      float4 v1 = *(const float4*)(br + 4);
      float4 v2 = *(const float4*)(br + 8);
      float4 v3 = *(const float4*)(br + 12);
      Bs[skl+ 0][srow]=v0.x; Bs[skl+ 1][srow]=v0.y; Bs[skl+ 2][srow]=v0.z; Bs[skl+ 3][srow]=v0.w;
      Bs[skl+ 4][srow]=v1.x; Bs[skl+ 5][srow]=v1.y; Bs[skl+ 6][srow]=v1.z; Bs[skl+ 7][srow]=v1.w;
      Bs[skl+ 8][srow]=v2.x; Bs[skl+ 9][srow]=v2.y; Bs[skl+10][srow]=v2.z; Bs[skl+11][srow]=v2.w;
      Bs[skl+12][srow]=v3.x; Bs[skl+13][srow]=v3.y; Bs[skl+14][srow]=v3.z; Bs[skl+15][srow]=v3.w;
    }
    __syncthreads();
#pragma unroll
    for (int kk = 0; kk < 32; ++kk) {
      float a[8], b[MR];
      *(float4*)&a[0] = *(const float4*)&As[kk][tn*4];
      *(float4*)&a[4] = *(const float4*)&As[kk][64 + tn*4];
      if (MR == 8) {
        *(float4*)&b[0] = *(const float4*)&Bs[kk][tm*4];
        *(float4*)&b[4] = *(const float4*)&Bs[kk][64 + tm*4];
      } else {
        *(float2*)&b[0] = *(const float2*)&Bs[kk][tm*6];
        *(float2*)&b[2] = *(const float2*)&Bs[kk][tm*6+2];
        *(float2*)&b[4] = *(const float2*)&Bs[kk][tm*6+4];
      }
#pragma unroll
      for (int i = 0; i < 8; ++i)
#pragma unroll
        for (int j = 0; j < MR; ++j) acc[i][j] = fmaf(a[i], b[j], acc[i][j]);
    }
  }

  float* Cb = C + (long)kz*ckstride + (size_t)(nt*128)*ldc + mt*MT;
#pragma unroll
  for (int ni = 0; ni < 8; ++ni) {
    int n = (ni < 4) ? tn*4 + ni : 64 + tn*4 + (ni - 4);
    float* cr = Cb + (size_t)n*ldc;
    if (MR == 8) {
      float4 s0 = make_float4(acc[ni][0], acc[ni][1], acc[ni][2], acc[ni][3]);
      float4 s1 = make_float4(acc[ni][4], acc[ni][5], acc[ni][6], acc[ni][7]);
      *(float4*)(cr + tm*4)      = s0;
      *(float4*)(cr + 64 + tm*4) = s1;
    } else {
#pragma unroll
      for (int j = 0; j < 6; ++j) {
        float v = acc[ni][j];
        if (MODE == 1) v += bp[tm*6 + j];
        cr[tm*6 + j] = v;
      }
    }
  }
}

// ---------------------------------------------------------------------------
// Patch embed + layer-0 RMSNorm. grid 256 = (bg)x(p), block 192.
// ---------------------------------------------------------------------------
__global__ __launch_bounds__(192, 1) void embed_kernel(
    const float* __restrict__ x, const float* __restrict__ w,
    const float* __restrict__ bias, const float* __restrict__ tok,
    const float* __restrict__ pos, const float* __restrict__ nw,
    float* __restrict__ res, float* __restrict__ hbuf, int is_f)
{
  const int t = threadIdx.x;
  const int p = blockIdx.x & 15;
  const int bg = blockIdx.x >> 4;
  __shared__ alignas(16) float xs[8*1792];
  __shared__ float lds_sq[9*192];
  __shared__ float lds_pt[9*16];
  __shared__ float lds_sc[9];

  for (int idx = t; idx < 8*1792; idx += 192) {
    int bb = idx / 1792;
    int r = idx - bb*1792;
    int b = bg*8 + bb;
    if (!is_f) {
      int c = r / 224;
      int rr = r - c*224;
      xs[idx] = x[((size_t)(b*8 + c)*224 + p*14)*16 + rr];
    } else {
      xs[idx] = x[((size_t)b*1792 + r)*16 + p];
    }
  }
  __syncthreads();

  float acc[8];
#pragma unroll
  for (int i = 0; i < 8; ++i) acc[i] = 0.f;
  const float4* wr = (const float4*)w + t*448;
  const float4* xv = (const float4*)xs;
  for (int k4 = 0; k4 < 448; ++k4) {
    float4 w4 = wr[k4];
#pragma unroll
    for (int bb = 0; bb < 8; ++bb) acc[bb] += dot4(xv[bb*448 + k4], w4);
  }
  float add = bias[t] + pos[p*DM + t];
  float v[8];
#pragma unroll
  for (int bb = 0; bb < 8; ++bb) {
    v[bb] = acc[bb] + add;
    lds_sq[bb*192 + t] = v[bb]*v[bb];
  }
  float v16 = tok[t] + pos[16*DM + t];
  lds_sq[8*192 + t] = v16*v16;
  __syncthreads();
  if (t < 144) {
    int r = t >> 4, j = t & 15;
    float s = 0.f;
#pragma unroll
    for (int k = 0; k < 12; ++k) s += lds_sq[r*192 + j + 16*k];
    lds_pt[t] = s;
  }
  __syncthreads();
  if (t < 9) {
    float s = 0.f;
#pragma unroll
    for (int j = 0; j < 16; ++j) s += lds_pt[t*16 + j];
    lds_sc[t] = rsqrtf(s*(1.0f/192.0f) + 1e-5f);
  }
  __syncthreads();
  float nwt = nw[t];
#pragma unroll
  for (int bb = 0; bb < 8; ++bb) {
    size_t base = (size_t)(bg*8 + bb)*ROW;
    res[base + p*DM + t]  = v[bb];
    hbuf[base + p*DM + t] = v[bb]*lds_sc[bb]*nwt;
  }
  if (p == 0) {
    float s16 = lds_sc[8];
#pragma unroll
    for (int bb = 0; bb < 8; ++bb) {
      size_t base = (size_t)(bg*8 + bb)*ROW;
      res[base + 16*DM + t]  = v16;
      hbuf[base + 16*DM + t] = v16*s16*nwt;
    }
  }
}

// ---------------------------------------------------------------------------
// Per-(s,b): conv+silu -> x_proj -> dt -> selective scan -> gate -> yg.
// grid 256, block 384 (thread = DI channel).
// ---------------------------------------------------------------------------
__global__ __launch_bounds__(384) void mid_kernel(
    const float* __restrict__ xzg, float* __restrict__ yg,
    MambaW wt, MambaW wf, int layer)
{
  const int t = threadIdx.x;
  const int sb = blockIdx.x;
  const MambaW W = (sb >= NB) ? wf : wt;
  __shared__ alignas(16) float lds_xx[SEQ*388];
  __shared__ alignas(16) float lds_dbl[748];
  const size_t nb = (size_t)sb*SEQ;

  // conv + silu (channel c = t), raw xz kept in regs for the shift
  float xr[SEQ];
  {
    const float4 cw = ((const float4*)(W.conv_w + (size_t)layer*DI*4))[t];
    const float cb = W.conv_b[layer*DI + t];
    float p0 = 0.f, p1 = 0.f, p2 = 0.f;
#pragma unroll
    for (int l = 0; l < SEQ; ++l) {
      float xz = xzg[(nb + l)*768 + t];
      float v = cb + xz*cw.w + p0*cw.z + p1*cw.y + p2*cw.x;
      p2 = p1; p1 = p0; p0 = xz;
      v = v / (1.f + __expf(-v));
      xr[l] = v;
      lds_xx[l*388 + t] = v;
    }
  }
  __syncthreads();

  // x_proj: 748 = 17*44 outputs
  {
    const float* XP = W.x_proj + (size_t)layer*44*DI;
#pragma unroll
    for (int rep = 0; rep < 2; ++rep) {
      int o = t + rep*384;
      if (o < 748) {
        int l = o / 44, j = o - l*44;
        const float4* wr = (const float4*)(XP + j*DI);
        const float4* xv4 = (const float4*)lds_xx + l*97;
        float a = 0.f;
        for (int k4 = 0; k4 < 96; ++k4) a += dot4(xv4[k4], wr[k4]);
        lds_dbl[o] = a;
      }
    }
  }
  __syncthreads();

  // dt + scan + gate, channel c = t
  {
    const int c = t;
    const float* dwr = W.dt_w + (size_t)layer*DI*12 + c*12;
    float w0[12];
#pragma unroll
    for (int r = 0; r < 12; ++r) w0[r] = dwr[r];
    const float dtb = W.dt_b[layer*DI + c];
    const float4* alr = (const float4*)(W.A_log + (size_t)layer*DI*16) + c*4;
    float Av[16];
#pragma unroll
    for (int q = 0; q < 4; ++q) {
      float4 a4 = alr[q];
      Av[q*4+0] = -__expf(a4.x); Av[q*4+1] = -__expf(a4.y);
      Av[q*4+2] = -__expf(a4.z); Av[q*4+3] = -__expf(a4.w);
    }
    const float Dp = W.D[layer*DI + c];
    float hst[16];
#pragma unroll
    for (int n = 0; n < 16; ++n) hst[n] = 0.f;
    for (int l = 0; l < SEQ; ++l) {
      float a = dtb;
#pragma unroll
      for (int r = 0; r < 12; ++r) a += lds_dbl[l*44 + r]*w0[r];
      float dt = (a > 20.f) ? a : log1pf(__expf(a));
      float xv = xr[l];
      const float4* dbv = (const float4*)(lds_dbl + l*44 + 12);
      float4 Bq[4], Cq[4];
      Bq[0]=dbv[0]; Bq[1]=dbv[1]; Bq[2]=dbv[2]; Bq[3]=dbv[3];
      Cq[0]=dbv[4]; Cq[1]=dbv[5]; Cq[2]=dbv[6]; Cq[3]=dbv[7];
      const float* Bs = (const float*)Bq;
      const float* Cs = (const float*)Cq;
      float y = 0.f;
      float dbx = dt * xv;
#pragma unroll
      for (int n = 0; n < 16; ++n) {
        float dA = __expf(dt * Av[n]);
        float hn = dA*hst[n] + dbx*Bs[n];
        hst[n] = hn;
        y += hn*Cs[n];
      }
      y += Dp * xv;
      float zv = xzg[(nb + l)*768 + DI + c];
      y *= zv / (1.f + __expf(-zv));
      yg[(nb + l)*DI + c] = y;
    }
  }
}

// ---------------------------------------------------------------------------
// Sum K-split partials + residual + RMSNorm for next layer (or final write).
// grid 256 (sb), block 192 (thread = d).
// ---------------------------------------------------------------------------
__global__ __launch_bounds__(192) void fuse_kernel(
    const float* __restrict__ part, float* __restrict__ res,
    float* __restrict__ hbuf, float* __restrict__ xfin,
    const float* __restrict__ nwT, const float* __restrict__ nwF,
    int layer, int last)
{
  const int d = threadIdx.x;
  const int sb = blockIdx.x;
  const size_t nb = (size_t)sb*SEQ;
  __shared__ float sq[SEQ*192];
  __shared__ float pt[SEQ*8];
  __shared__ float sc[SEQ];

  float v[SEQ];
#pragma unroll
  for (int l = 0; l < SEQ; ++l) {
    size_t idx = (nb + l)*DM + d;
    float s = part[idx] + part[(size_t)N192 + idx]
            + part[2*(size_t)N192 + idx] + part[3*(size_t)N192 + idx];
    if (!last) {
      s += res[idx];
      res[idx] = s;
      v[l] = s;
      sq[l*192 + d] = s*s;
    } else {
      xfin[idx] = s;
    }
  }
  if (last) return;
  __syncthreads();
  if (d < 136) {
    int l = d >> 3, j = d & 7;
    float s = 0.f;
#pragma unroll
    for (int q = 0; q < 24; ++q) s += sq[l*192 + j + 8*q];
    pt[d] = s;
  }
  __syncthreads();
  if (d < SEQ) {
    float s = 0.f;
#pragma unroll
    for (int j = 0; j < 8; ++j) s += pt[d*8 + j];
    sc[d] = rsqrtf(s*(1.0f/192.0f) + 1e-5f);
  }
  __syncthreads();
  const float* nw = ((sb < NB) ? nwT : nwF) + (size_t)(layer + 1)*DM;
  float nwd = nw[d];
#pragma unroll
  for (int l = 0; l < SEQ; ++l)
    hbuf[(nb + l)*DM + d] = v[l]*sc[l]*nwd;
}

// ---------------------------------------------------------------------------
// Attention core (query row 16 only, K/V precomputed in kvg) + MLP heads.
// grid 128 (b), block 192.
// ---------------------------------------------------------------------------
__global__ __launch_bounds__(192) void attn_core_kernel(
    const float* __restrict__ xfin, const float* __restrict__ kvg,
    const float* __restrict__ w1, const float* __restrict__ b1,
    const float* __restrict__ w2, const float* __restrict__ b2,
    const float* __restrict__ c1w, const float* __restrict__ c1b,
    const float* __restrict__ c2w, const float* __restrict__ c2b,
    const float* __restrict__ p1w, const float* __restrict__ p1b,
    const float* __restrict__ p2w, const float* __restrict__ p2b,
    float* __restrict__ out)
{
  const int d = threadIdx.x;
  const int b = blockIdx.x;
  __shared__ alignas(16) float lds_t16[DM];
  __shared__ alignas(16) float lds_q[DM];
  __shared__ alignas(16) float lds_o[DM];
  __shared__ alignas(16) float lds_t1[DM];
  __shared__ alignas(16) float lds_feat[DM];
  __shared__ alignas(16) float lds_hc[512];
  __shared__ alignas(16) float lds_hp[512];

  lds_t16[d] = xfin[((size_t)b*SEQ + 16)*DM + d];
  __syncthreads();

  for (int pass = 0; pass < 2; ++pass) {
    const float* wa = pass ? w2 : w1;
    const float* ba = pass ? b2 : b1;
    // Q projection of single query row
    {
      const float* qsrc = pass ? lds_t1 : lds_t16;
      const float4* wr = (const float4*)wa + d*48;
      const float4* a4 = (const float4*)qsrc;
      float acc = ba[d];
      for (int k4 = 0; k4 < 48; ++k4) acc += dot4(a4[k4], wr[k4]);
      lds_q[d] = acc;
    }
    __syncthreads();
    // scores + softmax + o
    {
      int h = d / 24;
      float4 q0 = *(const float4*)&lds_q[h*24];
      float4 q1 = *(const float4*)&lds_q[h*24+4];
      float4 q2 = *(const float4*)&lds_q[h*24+8];
      float4 q3 = *(const float4*)&lds_q[h*24+12];
      float4 q4 = *(const float4*)&lds_q[h*24+16];
      float4 q5 = *(const float4*)&lds_q[h*24+20];
      float scs[SEQ];
      float mx = -1e30f;
#pragma unroll
      for (int lk = 0; lk < SEQ; ++lk) {
        const float4* kr = (const float4*)(kvg + ((size_t)b*SEQ + lk)*768 + pass*384 + h*24);
        float s_ = dot4(q0,kr[0]) + dot4(q1,kr[1]) + dot4(q2,kr[2])
                 + dot4(q3,kr[3]) + dot4(q4,kr[4]) + dot4(q5,kr[5]);
        s_ *= 0.20412414523193154f; // 1/sqrt(24)
        scs[lk] = s_;
        mx = fmaxf(mx, s_);
      }
      float den = 0.f;
#pragma unroll
      for (int lk = 0; lk < SEQ; ++lk) { float e = __expf(scs[lk]-mx); scs[lk]=e; den += e; }
      float inv = 1.f/den;
      float o = 0.f;
#pragma unroll
      for (int lk = 0; lk < SEQ; ++lk)
        o += scs[lk] * kvg[((size_t)b*SEQ + lk)*768 + pass*384 + DM + d];
      lds_o[d] = o*inv;
    }
    __syncthreads();
    // output projection
    {
      const float4* wr = (const float4*)(wa + 3*DM*DM) + d*48;
      const float4* a4 = (const float4*)lds_o;
      float acc = ba[3*DM + d];
      for (int k4 = 0; k4 < 48; ++k4) acc += dot4(a4[k4], wr[k4]);
      if (pass == 0) lds_t1[d] = acc;
      else lds_feat[d] = acc + lds_t16[d];
    }
    __syncthreads();
  }

  for (int u = d; u < 512; u += 192) {
    const float4* wc = (const float4*)c1w + u*48;
    const float4* wp = (const float4*)p1w + u*48;
    const float4* fv = (const float4*)lds_feat;
    float a1 = c1b[u], a2 = p1b[u];
    for (int k4 = 0; k4 < 48; ++k4) {
      float4 f4 = fv[k4];
      a1 += dot4(f4, wc[k4]);
      a2 += dot4(f4, wp[k4]);
    }
    lds_hc[u] = fmaxf(a1, 0.f);
    lds_hp[u] = fmaxf(a2, 0.f);
  }
  __syncthreads();
  if (d < 10) {
    const float4* wr = (const float4*)c2w + d*128;
    float acc = c2b[d];
    for (int k4 = 0; k4 < 128; ++k4) acc += dot4(((const float4*)lds_hc)[k4], wr[k4]);
    out[b*10 + d] = acc;
  }
  if (d >= 64 && d < 67) {
    int j = d - 64;
    const float4* wr = (const float4*)p2w + j*128;
    float acc = p2b[j];
    for (int k4 = 0; k4 < 128; ++k4) acc += dot4(((const float4*)lds_hp)[k4], wr[k4]);
    out[1280 + b*3 + j] = acc;
  }
}

extern "C" void kernel_launch(void* const* d_in, const int* in_sizes, int n_in,
                              void* d_out, int out_size, void* d_ws, size_t ws_size,
                              hipStream_t stream)
{
  (void)in_sizes; (void)n_in; (void)out_size; (void)ws_size;
  const float* x    = (const float*)d_in[0];
  const float* tpw  = (const float*)d_in[1];
  const float* tpb  = (const float*)d_in[2];
  const float* fpw  = (const float*)d_in[3];
  const float* fpb  = (const float*)d_in[4];
  const float* ttok = (const float*)d_in[5];
  const float* ftok = (const float*)d_in[6];
  const float* tpos = (const float*)d_in[7];
  const float* fpos = (const float*)d_in[8];
  MambaW wt { (const float*)d_in[9],  (const float*)d_in[10], (const float*)d_in[11],
              (const float*)d_in[12], (const float*)d_in[13], (const float*)d_in[14],
              (const float*)d_in[15], (const float*)d_in[16], (const float*)d_in[17],
              (const float*)d_in[18] };
  MambaW wf { (const float*)d_in[19], (const float*)d_in[20], (const float*)d_in[21],
              (const float*)d_in[22], (const float*)d_in[23], (const float*)d_in[24],
              (const float*)d_in[25], (const float*)d_in[26], (const float*)d_in[27],
              (const float*)d_in[28] };
  const float* attw  = (const float*)d_in[29];
  const float* attb  = (const float*)d_in[30];
  const float* attw2 = (const float*)d_in[31];
  const float* attb2 = (const float*)d_in[32];
  const float* c1w = (const float*)d_in[33];
  const float* c1b = (const float*)d_in[34];
  const float* c2w = (const float*)d_in[35];
  const float* c2b = (const float*)d_in[36];
  const float* p1w = (const float*)d_in[37];
  const float* p1b = (const float*)d_in[38];
  const float* p2w = (const float*)d_in[39];
  const float* p2b = (const float*)d_in[40];

  float* ws = (float*)d_ws;
  float* res  = ws;                        // N192
  float* hbuf = ws + (size_t)N192;         // N192
  float* xfin = ws + 2*(size_t)N192;       // N192
  float* xzg  = ws + 3*(size_t)N192;       // NROWS*768 = 4*N192 (aliased as part)
  float* part = xzg;                       // 4 x N192 K-split partials
  float* yg   = ws + 7*(size_t)N192;       // NROWS*384 = 2*N192 (aliased as kvg)
  float* kvg  = yg;                        // 2176*768 = 2*N192

  embed_kernel<<<256, 192, 0, stream>>>(x, tpw, tpb, ttok, tpos, wt.norm_w,
                                        res, hbuf, 0);
  embed_kernel<<<256, 192, 0, stream>>>(x, fpw, fpb, ftok, fpos, wf.norm_w,
                                        res + (size_t)NB*ROW, hbuf + (size_t)NB*ROW, 1);

  for (int i = 0; i < DEPTH; ++i) {
    gemm_kernel<8,0><<<dim3(6,34,1), 256, 0, stream>>>(
        hbuf, DM, DM,
        wt.in_proj + (size_t)i*768*DM, wf.in_proj + (size_t)i*768*DM, DM,
        nullptr, nullptr, xzg, 768, 0);
    mid_kernel<<<256, 384, 0, stream>>>(xzg, yg, wt, wf, i);
    gemm_kernel<6,0><<<dim3(2,34,4), 256, 0, stream>>>(
        yg, DI, 96,
        wt.out_proj + (size_t)i*DM*DI, wf.out_proj + (size_t)i*DM*DI, DI,
        nullptr, nullptr, part, DM, (long)N192);
    fuse_kernel<<<256, 192, 0, stream>>>(part, res, hbuf, xfin,
        wt.norm_w, wf.norm_w, i, (i == DEPTH-1) ? 1 : 0);
  }

  // K/V for both attention passes from f-stream rows
  gemm_kernel<6,1><<<dim3(8,17,1), 256, 0, stream>>>(
      xfin + (size_t)NB*ROW, DM, DM,
      attw, attw2, DM, attb, attb2, kvg, 768, 0);
  attn_core_kernel<<<128, 192, 0, stream>>>(xfin, kvg,
      attw, attb, attw2, attb2,
      c1w, c1b, c2w, c2b, p1w, p1b, p2w, p2b, (float*)d_out);
}

// Round 4
// 1583.283 us; speedup vs baseline: 1.3612x; 1.1879x over previous
//
#include <hip/hip_runtime.h>
#include <math.h>

#define NB 128
#define SEQ 17
#define DM 192
#define DI 384
#define DEPTH 12
#define ROW (SEQ*DM)       // 3264
#define NROWS 4352         // 2*NB*SEQ
#define N192 (NROWS*DM)    // 835584
#define C1IP (DEPTH*2*DI*DM)   // 1769472 (one stream's in_proj elements)
#define C2OP (DEPTH*DM*DI)     // 884736  (one stream's out_proj elements)

typedef __attribute__((ext_vector_type(8))) short bf16x8;
typedef __attribute__((ext_vector_type(4))) float f32x4;

struct MambaW {
  const float* norm_w;
  const float* in_proj;
  const float* conv_w;
  const float* conv_b;
  const float* x_proj;
  const float* dt_w;
  const float* dt_b;
  const float* A_log;
  const float* D;
  const float* out_proj;
};

__device__ __forceinline__ float dot4(float4 a, float4 b) {
  return a.x*b.x + a.y*b.y + a.z*b.z + a.w*b.w;
}
__device__ __forceinline__ unsigned short f2bf(float f) {
  unsigned int u = __float_as_uint(f);
  u += 0x7FFFu + ((u >> 16) & 1u);
  return (unsigned short)(u >> 16);
}
__device__ __forceinline__ float bf2f(unsigned short h) {
  return __uint_as_float(((unsigned int)h) << 16);
}
__device__ __forceinline__ void split2(float v, unsigned short& h, unsigned short& l) {
  h = f2bf(v);
  l = f2bf(v - bf2f(h));
}

// ---------------------------------------------------------------------------
// Weight decompose fp32 -> bf16 hi/lo. grid (gx, 2): y selects src array;
// outputs concatenated [y=0 | y=1].
// ---------------------------------------------------------------------------
__global__ __launch_bounds__(256) void decomp_kernel(
    const float* __restrict__ s0, const float* __restrict__ s1,
    unsigned short* __restrict__ hi, unsigned short* __restrict__ lo, int nquads)
{
  const float* s = blockIdx.y ? s1 : s0;
  size_t base = (size_t)blockIdx.y * nquads;
  for (size_t i = (size_t)blockIdx.x*256 + threadIdx.x; i < (size_t)nquads;
       i += (size_t)gridDim.x*256) {
    float4 v = ((const float4*)s)[i];
    ushort4 h, l;
    split2(v.x, h.x, l.x); split2(v.y, h.y, l.y);
    split2(v.z, h.z, l.z); split2(v.w, h.w, l.w);
    ((ushort4*)hi)[base + i] = h;
    ((ushort4*)lo)[base + i] = l;
  }
}

// ---------------------------------------------------------------------------
// Split-bf16 MFMA GEMM: C[n][m] = sum_k A[n][k]*B[m][k].
// Tile 64(n) x MT(m), K-step 32, 256 threads = 4 waves (wave w: rows w*16..+16).
// A,B given as bf16 hi/lo pairs; 3 MFMAs per k-step recover ~fp32 precision.
// B selected per n-tile: nt<34 -> Bt (t-stream rows), else Bf.
// ---------------------------------------------------------------------------
template<int MT>
__global__ __launch_bounds__(256) void gemm_mfma(
    const unsigned short* __restrict__ Ahi, const unsigned short* __restrict__ Alo, int lda,
    const unsigned short* __restrict__ BtHi, const unsigned short* __restrict__ BtLo,
    const unsigned short* __restrict__ BfHi, const unsigned short* __restrict__ BfLo,
    int ldb, int kchunk, float* __restrict__ C, int ldc, long ckstride)
{
  const int t = threadIdx.x;
  const int mt = blockIdx.x, nt = blockIdx.y, kz = blockIdx.z;
  __shared__ alignas(16) unsigned short sAh[64*40], sAl[64*40];
  __shared__ alignas(16) unsigned short sBh[MT*40], sBl[MT*40];

  const bool isT = (nt < 34);
  const unsigned short* aH = Ahi + (size_t)(nt*64)*lda + kz*kchunk;
  const unsigned short* aL = Alo + (size_t)(nt*64)*lda + kz*kchunk;
  const unsigned short* bH = (isT ? BtHi : BfHi) + (size_t)(mt*MT)*ldb + kz*kchunk;
  const unsigned short* bL = (isT ? BtLo : BfLo) + (size_t)(mt*MT)*ldb + kz*kchunk;

  const int wave = t >> 6, lane = t & 63;
  const int arow = wave*16 + (lane & 15);
  const int kb   = (lane >> 4) * 8;

  f32x4 acc[MT/16];
#pragma unroll
  for (int mb = 0; mb < MT/16; ++mb) acc[mb] = (f32x4){0.f, 0.f, 0.f, 0.f};

  const int srow = t >> 2, sseg = (t & 3) * 8;

  for (int kt = 0; kt < kchunk; kt += 32) {
    __syncthreads();
    *(uint4*)(sAh + srow*40 + sseg) = *(const uint4*)(aH + (size_t)srow*lda + kt + sseg);
    *(uint4*)(sAl + srow*40 + sseg) = *(const uint4*)(aL + (size_t)srow*lda + kt + sseg);
#pragma unroll
    for (int rep = 0; rep < MT/64; ++rep) {
      int r2 = rep*64 + srow;
      *(uint4*)(sBh + r2*40 + sseg) = *(const uint4*)(bH + (size_t)r2*ldb + kt + sseg);
      *(uint4*)(sBl + r2*40 + sseg) = *(const uint4*)(bL + (size_t)r2*ldb + kt + sseg);
    }
    __syncthreads();
    bf16x8 ah = *(const bf16x8*)(sAh + arow*40 + kb);
    bf16x8 al = *(const bf16x8*)(sAl + arow*40 + kb);
#pragma unroll
    for (int mb = 0; mb < MT/16; ++mb) {
      bf16x8 bh = *(const bf16x8*)(sBh + (mb*16 + (lane & 15))*40 + kb);
      bf16x8 bl = *(const bf16x8*)(sBl + (mb*16 + (lane & 15))*40 + kb);
      acc[mb] = __builtin_amdgcn_mfma_f32_16x16x32_bf16(al, bh, acc[mb], 0, 0, 0);
      acc[mb] = __builtin_amdgcn_mfma_f32_16x16x32_bf16(ah, bl, acc[mb], 0, 0, 0);
      acc[mb] = __builtin_amdgcn_mfma_f32_16x16x32_bf16(ah, bh, acc[mb], 0, 0, 0);
    }
  }

  float* Cb = C + (long)kz*ckstride
            + (size_t)(nt*64 + wave*16 + (lane >> 4)*4)*ldc + mt*MT + (lane & 15);
#pragma unroll
  for (int mb = 0; mb < MT/16; ++mb)
#pragma unroll
    for (int r = 0; r < 4; ++r)
      Cb[(size_t)r*ldc + mb*16] = acc[mb][r];
}

// ---------------------------------------------------------------------------
// Patch embed (t and f merged) + layer-0 RMSNorm. grid 1024 = is_f x bg(32) x p(16),
// block 192, 4 batches/block. Writes res (fp32) + hbuf hi/lo (bf16 split).
// ---------------------------------------------------------------------------
__global__ __launch_bounds__(192) void embed_kernel(
    const float* __restrict__ x,
    const float* __restrict__ wT, const float* __restrict__ bT,
    const float* __restrict__ tokT, const float* __restrict__ posT,
    const float* __restrict__ nwT,
    const float* __restrict__ wF, const float* __restrict__ bF,
    const float* __restrict__ tokF, const float* __restrict__ posF,
    const float* __restrict__ nwF,
    float* __restrict__ res,
    unsigned short* __restrict__ hHi, unsigned short* __restrict__ hLo)
{
  const int t = threadIdx.x;
  int bx = blockIdx.x;
  const int is_f = bx >> 9;
  bx &= 511;
  const int p = bx & 15;
  const int bg = bx >> 4;          // 0..31, batches bg*4..bg*4+3
  const float* w    = is_f ? wF : wT;
  const float* bias = is_f ? bF : bT;
  const float* tok  = is_f ? tokF : tokT;
  const float* pos  = is_f ? posF : posT;
  const float* nw   = is_f ? nwF : nwT;
  const size_t sbase = is_f ? (size_t)NB*ROW : 0;

  __shared__ alignas(16) float xs[4*1792];
  __shared__ float lds_sq[5*192];
  __shared__ float lds_pt[5*16];
  __shared__ float lds_sc[5];

  for (int idx = t; idx < 4*1792; idx += 192) {
    int bb = idx / 1792;
    int r = idx - bb*1792;
    int b = bg*4 + bb;
    if (!is_f) {
      int c = r / 224;
      int rr = r - c*224;
      xs[idx] = x[((size_t)(b*8 + c)*224 + p*14)*16 + rr];
    } else {
      xs[idx] = x[((size_t)b*1792 + r)*16 + p];
    }
  }
  __syncthreads();

  float acc[4];
#pragma unroll
  for (int i = 0; i < 4; ++i) acc[i] = 0.f;
  const float4* wr = (const float4*)w + t*448;
  const float4* xv = (const float4*)xs;
  for (int k4 = 0; k4 < 448; ++k4) {
    float4 w4 = wr[k4];
#pragma unroll
    for (int bb = 0; bb < 4; ++bb) acc[bb] += dot4(xv[bb*448 + k4], w4);
  }
  float add = bias[t] + pos[p*DM + t];
  float v[4];
#pragma unroll
  for (int bb = 0; bb < 4; ++bb) {
    v[bb] = acc[bb] + add;
    lds_sq[bb*192 + t] = v[bb]*v[bb];
  }
  float v16 = tok[t] + pos[16*DM + t];
  lds_sq[4*192 + t] = v16*v16;
  __syncthreads();
  if (t < 80) {
    int r = t >> 4, j = t & 15;
    float s = 0.f;
#pragma unroll
    for (int k = 0; k < 12; ++k) s += lds_sq[r*192 + j + 16*k];
    lds_pt[t] = s;
  }
  __syncthreads();
  if (t < 5) {
    float s = 0.f;
#pragma unroll
    for (int j = 0; j < 16; ++j) s += lds_pt[t*16 + j];
    lds_sc[t] = rsqrtf(s*(1.0f/192.0f) + 1e-5f);
  }
  __syncthreads();
  float nwt = nw[t];
#pragma unroll
  for (int bb = 0; bb < 4; ++bb) {
    size_t base = sbase + (size_t)(bg*4 + bb)*ROW + p*DM + t;
    res[base] = v[bb];
    unsigned short h, l;
    split2(v[bb]*lds_sc[bb]*nwt, h, l);
    hHi[base] = h; hLo[base] = l;
  }
  if (p == 0) {
    float s16 = lds_sc[4];
#pragma unroll
    for (int bb = 0; bb < 4; ++bb) {
      size_t base = sbase + (size_t)(bg*4 + bb)*ROW + 16*DM + t;
      res[base] = v16;
      unsigned short h, l;
      split2(v16*s16*nwt, h, l);
      hHi[base] = h; hLo[base] = l;
    }
  }
}

// ---------------------------------------------------------------------------
// Per-(s,b): conv+silu -> x_proj -> dt -> selective scan -> gate -> y hi/lo.
// grid 256, block 384 (thread = DI channel).
// ---------------------------------------------------------------------------
__global__ __launch_bounds__(384) void mid_kernel(
    const float* __restrict__ xzg,
    unsigned short* __restrict__ yHi, unsigned short* __restrict__ yLo,
    MambaW wt, MambaW wf, int layer)
{
  const int t = threadIdx.x;
  const int sb = blockIdx.x;
  const MambaW W = (sb >= NB) ? wf : wt;
  __shared__ alignas(16) float lds_xx[SEQ*388];
  __shared__ alignas(16) float lds_dbl[748];
  const size_t nb = (size_t)sb*SEQ;

  float xr[SEQ];
  {
    const float4 cw = ((const float4*)(W.conv_w + (size_t)layer*DI*4))[t];
    const float cb = W.conv_b[layer*DI + t];
    float p0 = 0.f, p1 = 0.f, p2 = 0.f;
#pragma unroll
    for (int l = 0; l < SEQ; ++l) {
      float xz = xzg[(nb + l)*768 + t];
      float v = cb + xz*cw.w + p0*cw.z + p1*cw.y + p2*cw.x;
      p2 = p1; p1 = p0; p0 = xz;
      v = v / (1.f + __expf(-v));
      xr[l] = v;
      lds_xx[l*388 + t] = v;
    }
  }
  __syncthreads();

  {
    const float* XP = W.x_proj + (size_t)layer*44*DI;
#pragma unroll
    for (int rep = 0; rep < 2; ++rep) {
      int o = t + rep*384;
      if (o < 748) {
        int l = o / 44, j = o - l*44;
        const float4* wr = (const float4*)(XP + j*DI);
        const float4* xv4 = (const float4*)lds_xx + l*97;
        float a = 0.f;
        for (int k4 = 0; k4 < 96; ++k4) a += dot4(xv4[k4], wr[k4]);
        lds_dbl[o] = a;
      }
    }
  }
  __syncthreads();

  {
    const int c = t;
    const float* dwr = W.dt_w + (size_t)layer*DI*12 + c*12;
    float w0[12];
#pragma unroll
    for (int r = 0; r < 12; ++r) w0[r] = dwr[r];
    const float dtb = W.dt_b[layer*DI + c];
    const float4* alr = (const float4*)(W.A_log + (size_t)layer*DI*16) + c*4;
    float Av[16];
#pragma unroll
    for (int q = 0; q < 4; ++q) {
      float4 a4 = alr[q];
      Av[q*4+0] = -__expf(a4.x); Av[q*4+1] = -__expf(a4.y);
      Av[q*4+2] = -__expf(a4.z); Av[q*4+3] = -__expf(a4.w);
    }
    const float Dp = W.D[layer*DI + c];
    float hst[16];
#pragma unroll
    for (int n = 0; n < 16; ++n) hst[n] = 0.f;
    for (int l = 0; l < SEQ; ++l) {
      float a = dtb;
#pragma unroll
      for (int r = 0; r < 12; ++r) a += lds_dbl[l*44 + r]*w0[r];
      float dt = (a > 20.f) ? a : log1pf(__expf(a));
      float xv = xr[l];
      const float4* dbv = (const float4*)(lds_dbl + l*44 + 12);
      float4 Bq[4], Cq[4];
      Bq[0]=dbv[0]; Bq[1]=dbv[1]; Bq[2]=dbv[2]; Bq[3]=dbv[3];
      Cq[0]=dbv[4]; Cq[1]=dbv[5]; Cq[2]=dbv[6]; Cq[3]=dbv[7];
      const float* Bs = (const float*)Bq;
      const float* Cs = (const float*)Cq;
      float y = 0.f;
      float dbx = dt * xv;
#pragma unroll
      for (int n = 0; n < 16; ++n) {
        float dA = __expf(dt * Av[n]);
        float hn = dA*hst[n] + dbx*Bs[n];
        hst[n] = hn;
        y += hn*Cs[n];
      }
      y += Dp * xv;
      float zv = xzg[(nb + l)*768 + DI + c];
      y *= zv / (1.f + __expf(-zv));
      unsigned short h, lo_;
      split2(y, h, lo_);
      size_t idx = (nb + l)*DI + c;
      yHi[idx] = h; yLo[idx] = lo_;
    }
  }
}

// ---------------------------------------------------------------------------
// Sum 2 K-split partials + residual + RMSNorm -> hbuf hi/lo (or final xfin).
// grid 256 (sb), block 192 (thread = d).
// ---------------------------------------------------------------------------
__global__ __launch_bounds__(192) void fuse_kernel(
    const float* __restrict__ part, float* __restrict__ res,
    unsigned short* __restrict__ hHi, unsigned short* __restrict__ hLo,
    float* __restrict__ xfin,
    const float* __restrict__ nwT, const float* __restrict__ nwF,
    int layer, int last)
{
  const int d = threadIdx.x;
  const int sb = blockIdx.x;
  const size_t nb = (size_t)sb*SEQ;
  __shared__ float sq[SEQ*192];
  __shared__ float pt[SEQ*8];
  __shared__ float sc[SEQ];

  float v[SEQ];
#pragma unroll
  for (int l = 0; l < SEQ; ++l) {
    size_t idx = (nb + l)*DM + d;
    float s = part[idx] + part[(size_t)N192 + idx];
    if (!last) {
      s += res[idx];
      res[idx] = s;
      v[l] = s;
      sq[l*192 + d] = s*s;
    } else {
      xfin[idx] = s;
    }
  }
  if (last) return;
  __syncthreads();
  if (d < 136) {
    int l = d >> 3, j = d & 7;
    float s = 0.f;
#pragma unroll
    for (int q = 0; q < 24; ++q) s += sq[l*192 + j + 8*q];
    pt[d] = s;
  }
  __syncthreads();
  if (d < SEQ) {
    float s = 0.f;
#pragma unroll
    for (int j = 0; j < 8; ++j) s += pt[d*8 + j];
    sc[d] = rsqrtf(s*(1.0f/192.0f) + 1e-5f);
  }
  __syncthreads();
  const float* nw = ((sb < NB) ? nwT : nwF) + (size_t)(layer + 1)*DM;
  float nwd = nw[d];
#pragma unroll
  for (int l = 0; l < SEQ; ++l) {
    unsigned short h, lo_;
    split2(v[l]*sc[l]*nwd, h, lo_);
    size_t idx = (nb + l)*DM + d;
    hHi[idx] = h; hLo[idx] = lo_;
  }
}

// ---------------------------------------------------------------------------
// Attention K/V GEMM (fp32 VALU), from round-3 MODE1 (verified). grid (8,17).
// ---------------------------------------------------------------------------
__global__ __launch_bounds__(256, 3) void gemm_kv(
    const float* __restrict__ A, int lda, int ktot,
    const float* __restrict__ Bt, const float* __restrict__ Bf, int ldb,
    const float* __restrict__ bias1, const float* __restrict__ bias2,
    float* __restrict__ C, int ldc)
{
  const int t  = threadIdx.x;
  const int mt = blockIdx.x, nt = blockIdx.y;
  __shared__ float As[32][132];
  __shared__ float Bs[32][100];

  int pass = mt >> 2, kv = (mt >> 1) & 1, half = mt & 1;
  const float* Bp = (pass ? Bf : Bt) + (size_t)(1+kv)*DM*DM + (size_t)(half*96)*ldb;
  const float* bp = (pass ? bias2 : bias1) + (1+kv)*DM + half*96;
  const float* Ap = A + (size_t)(nt*128)*lda;

  const int tn = t & 15, tm = t >> 4;
  float acc[8][6];
#pragma unroll
  for (int i = 0; i < 8; ++i)
#pragma unroll
    for (int j = 0; j < 6; ++j) acc[i][j] = 0.f;

  const int srow = t >> 1;
  const int skl  = (t & 1) * 16;

  for (int kt = 0; kt < ktot; kt += 32) {
    __syncthreads();
    {
      const float* ar = Ap + (size_t)srow*lda + kt + skl;
      float4 v0 = *(const float4*)(ar + 0);
      float4 v1 = *(const float4*)(ar + 4);
      float4 v2 = *(const float4*)(ar + 8);
      float4 v3 = *(const float4*)(ar + 12);
      As[skl+ 0][srow]=v0.x; As[skl+ 1][srow]=v0.y; As[skl+ 2][srow]=v0.z; As[skl+ 3][srow]=v0.w;
      As[skl+ 4][srow]=v1.x; As[skl+ 5][srow]=v1.y; As[skl+ 6][srow]=v1.z; As[skl+ 7][srow]=v1.w;
      As[skl+ 8][srow]=v2.x; As[skl+ 9][srow]=v2.y; As[skl+10][srow]=v2.z; As[skl+11][srow]=v2.w;
      As[skl+12][srow]=v3.x; As[skl+13][srow]=v3.y; As[skl+14][srow]=v3.z; As[skl+15][srow]=v3.w;
    }
    if (srow < 96) {
      const float* br = Bp + (size_t)srow*ldb + kt + skl;
      float4 v0 = *(const float4*)(br + 0);
      float4 v1 = *(const float4*)(br + 4);
      float4 v2 = *(const float4*)(br + 8);
      float4 v3 = *(const float4*)(br + 12);
      Bs[skl+ 0][srow]=v0.x; Bs[skl+ 1][srow]=v0.y; Bs[skl+ 2][srow]=v0.z; Bs[skl+ 3][srow]=v0.w;
      Bs[skl+ 4][srow]=v1.x; Bs[skl+ 5][srow]=v1.y; Bs[skl+ 6][srow]=v1.z; Bs[skl+ 7][srow]=v1.w;
      Bs[skl+ 8][srow]=v2.x; Bs[skl+ 9][srow]=v2.y; Bs[skl+10][srow]=v2.z; Bs[skl+11][srow]=v2.w;
      Bs[skl+12][srow]=v3.x; Bs[skl+13][srow]=v3.y; Bs[skl+14][srow]=v3.z; Bs[skl+15][srow]=v3.w;
    }
    __syncthreads();
#pragma unroll
    for (int kk = 0; kk < 32; ++kk) {
      float a[8], b[6];
      *(float4*)&a[0] = *(const float4*)&As[kk][tn*4];
      *(float4*)&a[4] = *(const float4*)&As[kk][64 + tn*4];
      *(float2*)&b[0] = *(const float2*)&Bs[kk][tm*6];
      *(float2*)&b[2] = *(const float2*)&Bs[kk][tm*6+2];
      *(float2*)&b[4] = *(const float2*)&Bs[kk][tm*6+4];
#pragma unroll
      for (int i = 0; i < 8; ++i)
#pragma unroll
        for (int j = 0; j < 6; ++j) acc[i][j] = fmaf(a[i], b[j], acc[i][j]);
    }
  }

  float* Cb = C + (size_t)(nt*128)*ldc + mt*96;
#pragma unroll
  for (int ni = 0; ni < 8; ++ni) {
    int n = (ni < 4) ? tn*4 + ni : 64 + tn*4 + (ni - 4);
    float* cr = Cb + (size_t)n*ldc;
#pragma unroll
    for (int j = 0; j < 6; ++j) cr[tm*6 + j] = acc[ni][j] + bp[tm*6 + j];
  }
}

// ---------------------------------------------------------------------------
// Attention core (query row 16 only) + MLP heads. grid 128 (b), block 192.
// ---------------------------------------------------------------------------
__global__ __launch_bounds__(192) void attn_core_kernel(
    const float* __restrict__ xfin, const float* __restrict__ kvg,
    const float* __restrict__ w1, const float* __restrict__ b1,
    const float* __restrict__ w2, const float* __restrict__ b2,
    const float* __restrict__ c1w, const float* __restrict__ c1b,
    const float* __restrict__ c2w, const float* __restrict__ c2b,
    const float* __restrict__ p1w, const float* __restrict__ p1b,
    const float* __restrict__ p2w, const float* __restrict__ p2b,
    float* __restrict__ out)
{
  const int d = threadIdx.x;
  const int b = blockIdx.x;
  __shared__ alignas(16) float lds_t16[DM];
  __shared__ alignas(16) float lds_q[DM];
  __shared__ alignas(16) float lds_o[DM];
  __shared__ alignas(16) float lds_t1[DM];
  __shared__ alignas(16) float lds_feat[DM];
  __shared__ alignas(16) float lds_hc[512];
  __shared__ alignas(16) float lds_hp[512];

  lds_t16[d] = xfin[((size_t)b*SEQ + 16)*DM + d];
  __syncthreads();

  for (int pass = 0; pass < 2; ++pass) {
    const float* wa = pass ? w2 : w1;
    const float* ba = pass ? b2 : b1;
    {
      const float* qsrc = pass ? lds_t1 : lds_t16;
      const float4* wr = (const float4*)wa + d*48;
      const float4* a4 = (const float4*)qsrc;
      float acc = ba[d];
      for (int k4 = 0; k4 < 48; ++k4) acc += dot4(a4[k4], wr[k4]);
      lds_q[d] = acc;
    }
    __syncthreads();
    {
      int h = d / 24;
      float4 q0 = *(const float4*)&lds_q[h*24];
      float4 q1 = *(const float4*)&lds_q[h*24+4];
      float4 q2 = *(const float4*)&lds_q[h*24+8];
      float4 q3 = *(const float4*)&lds_q[h*24+12];
      float4 q4 = *(const float4*)&lds_q[h*24+16];
      float4 q5 = *(const float4*)&lds_q[h*24+20];
      float scs[SEQ];
      float mx = -1e30f;
#pragma unroll
      for (int lk = 0; lk < SEQ; ++lk) {
        const float4* kr = (const float4*)(kvg + ((size_t)b*SEQ + lk)*768 + pass*384 + h*24);
        float s_ = dot4(q0,kr[0]) + dot4(q1,kr[1]) + dot4(q2,kr[2])
                 + dot4(q3,kr[3]) + dot4(q4,kr[4]) + dot4(q5,kr[5]);
        s_ *= 0.20412414523193154f;
        scs[lk] = s_;
        mx = fmaxf(mx, s_);
      }
      float den = 0.f;
#pragma unroll
      for (int lk = 0; lk < SEQ; ++lk) { float e = __expf(scs[lk]-mx); scs[lk]=e; den += e; }
      float inv = 1.f/den;
      float o = 0.f;
#pragma unroll
      for (int lk = 0; lk < SEQ; ++lk)
        o += scs[lk] * kvg[((size_t)b*SEQ + lk)*768 + pass*384 + DM + d];
      lds_o[d] = o*inv;
    }
    __syncthreads();
    {
      const float4* wr = (const float4*)(wa + 3*DM*DM) + d*48;
      const float4* a4 = (const float4*)lds_o;
      float acc = ba[3*DM + d];
      for (int k4 = 0; k4 < 48; ++k4) acc += dot4(a4[k4], wr[k4]);
      if (pass == 0) lds_t1[d] = acc;
      else lds_feat[d] = acc + lds_t16[d];
    }
    __syncthreads();
  }

  for (int u = d; u < 512; u += 192) {
    const float4* wc = (const float4*)c1w + u*48;
    const float4* wp = (const float4*)p1w + u*48;
    const float4* fv = (const float4*)lds_feat;
    float a1 = c1b[u], a2 = p1b[u];
    for (int k4 = 0; k4 < 48; ++k4) {
      float4 f4 = fv[k4];
      a1 += dot4(f4, wc[k4]);
      a2 += dot4(f4, wp[k4]);
    }
    lds_hc[u] = fmaxf(a1, 0.f);
    lds_hp[u] = fmaxf(a2, 0.f);
  }
  __syncthreads();
  if (d < 10) {
    const float4* wr = (const float4*)c2w + d*128;
    float acc = c2b[d];
    for (int k4 = 0; k4 < 128; ++k4) acc += dot4(((const float4*)lds_hc)[k4], wr[k4]);
    out[b*10 + d] = acc;
  }
  if (d >= 64 && d < 67) {
    int j = d - 64;
    const float4* wr = (const float4*)p2w + j*128;
    float acc = p2b[j];
    for (int k4 = 0; k4 < 128; ++k4) acc += dot4(((const float4*)lds_hp)[k4], wr[k4]);
    out[1280 + b*3 + j] = acc;
  }
}

extern "C" void kernel_launch(void* const* d_in, const int* in_sizes, int n_in,
                              void* d_out, int out_size, void* d_ws, size_t ws_size,
                              hipStream_t stream)
{
  (void)in_sizes; (void)n_in; (void)out_size; (void)ws_size;
  const float* x    = (const float*)d_in[0];
  const float* tpw  = (const float*)d_in[1];
  const float* tpb  = (const float*)d_in[2];
  const float* fpw  = (const float*)d_in[3];
  const float* fpb  = (const float*)d_in[4];
  const float* ttok = (const float*)d_in[5];
  const float* ftok = (const float*)d_in[6];
  const float* tpos = (const float*)d_in[7];
  const float* fpos = (const float*)d_in[8];
  MambaW wt { (const float*)d_in[9],  (const float*)d_in[10], (const float*)d_in[11],
              (const float*)d_in[12], (const float*)d_in[13], (const float*)d_in[14],
              (const float*)d_in[15], (const float*)d_in[16], (const float*)d_in[17],
              (const float*)d_in[18] };
  MambaW wf { (const float*)d_in[19], (const float*)d_in[20], (const float*)d_in[21],
              (const float*)d_in[22], (const float*)d_in[23], (const float*)d_in[24],
              (const float*)d_in[25], (const float*)d_in[26], (const float*)d_in[27],
              (const float*)d_in[28] };
  const float* attw  = (const float*)d_in[29];
  const float* attb  = (const float*)d_in[30];
  const float* attw2 = (const float*)d_in[31];
  const float* attb2 = (const float*)d_in[32];
  const float* c1w = (const float*)d_in[33];
  const float* c1b = (const float*)d_in[34];
  const float* c2w = (const float*)d_in[35];
  const float* c2b = (const float*)d_in[36];
  const float* p1w = (const float*)d_in[37];
  const float* p1b = (const float*)d_in[38];
  const float* p2w = (const float*)d_in[39];
  const float* p2b = (const float*)d_in[40];

  float* ws = (float*)d_ws;
  size_t off = 0;
  float* res  = ws + off; off += (size_t)N192;
  float* xfin = ws + off; off += (size_t)N192;
  float* xzg  = ws + off; off += (size_t)4*N192;       // NROWS x 768
  float* part = ws + off; off += (size_t)2*N192;       // 2 K-split partials (also kvg)
  unsigned short* hHi = (unsigned short*)(ws + off); off += (size_t)N192/2;
  unsigned short* hLo = (unsigned short*)(ws + off); off += (size_t)N192/2;
  unsigned short* yHi = (unsigned short*)(ws + off); off += (size_t)N192;   // NROWS x 384
  unsigned short* yLo = (unsigned short*)(ws + off); off += (size_t)N192;
  unsigned short* ipHi = (unsigned short*)(ws + off); off += (size_t)C1IP; // 2 streams
  unsigned short* ipLo = (unsigned short*)(ws + off); off += (size_t)C1IP;
  unsigned short* opHi = (unsigned short*)(ws + off); off += (size_t)C2OP;
  unsigned short* opLo = (unsigned short*)(ws + off); off += (size_t)C2OP;
  float* kvg = part;

  decomp_kernel<<<dim3(512, 2), 256, 0, stream>>>(wt.in_proj, wf.in_proj,
                                                  ipHi, ipLo, C1IP/4);
  decomp_kernel<<<dim3(512, 2), 256, 0, stream>>>(wt.out_proj, wf.out_proj,
                                                  opHi, opLo, C2OP/4);
  embed_kernel<<<1024, 192, 0, stream>>>(x,
      tpw, tpb, ttok, tpos, wt.norm_w,
      fpw, fpb, ftok, fpos, wf.norm_w,
      res, hHi, hLo);

  for (int i = 0; i < DEPTH; ++i) {
    const size_t ipo = (size_t)i*2*DI*DM;
    const size_t opo = (size_t)i*DM*DI;
    gemm_mfma<128><<<dim3(6, 68, 1), 256, 0, stream>>>(
        hHi, hLo, DM,
        ipHi + ipo, ipLo + ipo, ipHi + C1IP + ipo, ipLo + C1IP + ipo,
        DM, DM /*kchunk=192*/, xzg, 768, 0);
    mid_kernel<<<256, 384, 0, stream>>>(xzg, yHi, yLo, wt, wf, i);
    gemm_mfma<64><<<dim3(3, 68, 2), 256, 0, stream>>>(
        yHi, yLo, DI,
        opHi + opo, opLo + opo, opHi + C2OP + opo, opLo + C2OP + opo,
        DI, 192, part, DM, (long)N192);
    fuse_kernel<<<256, 192, 0, stream>>>(part, res, hHi, hLo, xfin,
        wt.norm_w, wf.norm_w, i, (i == DEPTH-1) ? 1 : 0);
  }

  gemm_kv<<<dim3(8, 17), 256, 0, stream>>>(
      xfin + (size_t)NB*ROW, DM, DM,
      attw, attw2, DM, attb, attb2, kvg, 768);
  attn_core_kernel<<<128, 192, 0, stream>>>(xfin, kvg,
      attw, attb, attw2, attb2,
      c1w, c1b, c2w, c2b, p1w, p1b, p2w, p2b, (float*)d_out);
}

// Round 7
// 1578.050 us; speedup vs baseline: 1.3657x; 1.0033x over previous
//
#include <hip/hip_runtime.h>
#include <math.h>

#define NB 128
#define SEQ 17
#define DM 192
#define DI 384
#define DEPTH 12
#define ROW (SEQ*DM)       // 3264
#define NROWS 4352         // 2*NB*SEQ
#define N192 (NROWS*DM)    // 835584
#define C1IP (DEPTH*2*DI*DM)   // 1769472 (one stream's in_proj elements)
#define C2OP (DEPTH*DM*DI)     // 884736  (one stream's out_proj elements)

typedef __attribute__((ext_vector_type(8))) short bf16x8;
typedef __attribute__((ext_vector_type(4))) float f32x4;

struct MambaW {
  const float* norm_w;
  const float* in_proj;
  const float* conv_w;
  const float* conv_b;
  const float* x_proj;
  const float* dt_w;
  const float* dt_b;
  const float* A_log;
  const float* D;
  const float* out_proj;
};

__device__ __forceinline__ float dot4(float4 a, float4 b) {
  return a.x*b.x + a.y*b.y + a.z*b.z + a.w*b.w;
}
__device__ __forceinline__ unsigned short f2bf(float f) {
  unsigned int u = __float_as_uint(f);
  u += 0x7FFFu + ((u >> 16) & 1u);
  return (unsigned short)(u >> 16);
}
__device__ __forceinline__ float bf2f(unsigned short h) {
  return __uint_as_float(((unsigned int)h) << 16);
}
__device__ __forceinline__ void split2(float v, unsigned short& h, unsigned short& l) {
  h = f2bf(v);
  l = f2bf(v - bf2f(h));
}

// ---------------------------------------------------------------------------
// Weight decompose fp32 -> bf16 hi/lo. grid (gx, 2): y selects src array;
// outputs concatenated [y=0 | y=1].  (verified R4)
// ---------------------------------------------------------------------------
__global__ __launch_bounds__(256) void decomp_kernel(
    const float* __restrict__ s0, const float* __restrict__ s1,
    unsigned short* __restrict__ hi, unsigned short* __restrict__ lo, int nquads)
{
  const float* s = blockIdx.y ? s1 : s0;
  size_t base = (size_t)blockIdx.y * nquads;
  for (size_t i = (size_t)blockIdx.x*256 + threadIdx.x; i < (size_t)nquads;
       i += (size_t)gridDim.x*256) {
    float4 v = ((const float4*)s)[i];
    ushort4 h, l;
    split2(v.x, h.x, l.x); split2(v.y, h.y, l.y);
    split2(v.z, h.z, l.z); split2(v.w, h.w, l.w);
    ((ushort4*)hi)[base + i] = h;
    ((ushort4*)lo)[base + i] = l;
  }
}

// ---------------------------------------------------------------------------
// NEW (R7): f-stream transpose.  xT[(b*16+p)*1792 + c*224 + kh] = x[b][c][kh][p].
// grid 1024 = (b,c), block 256.  Coalesced read of x[b][c][:][:] (3584 floats),
// LDS 16x225 transpose, contiguous 224-float-run writes.  Kills the 16x
// overfetch R4's embed f-gather had (58 MB -> ~14 MB).
// ---------------------------------------------------------------------------
__global__ __launch_bounds__(256) void transpose_f_kernel(
    const float* __restrict__ x, float* __restrict__ xT)
{
  const int t = threadIdx.x;
  const int b = blockIdx.x >> 3, c = blockIdx.x & 7;
  __shared__ float ts[16][225];
  const float* xp = x + (size_t)(b*8 + c)*3584;
  for (int idx = t; idx < 3584; idx += 256)
    ts[idx & 15][idx >> 4] = xp[idx];
  __syncthreads();
  for (int o = t; o < 3584; o += 256) {
    int p = o / 224, kh = o - p*224;
    xT[((size_t)b*16 + p)*1792 + c*224 + kh] = ts[p][kh];
  }
}

// ---------------------------------------------------------------------------
// Patch embed (t and f merged) + layer-0 RMSNorm. grid 1024 = is_f x bg(32) x p(16),
// block 192, 4 batches/block. Writes res (fp32) + hbuf hi/lo (bf16 split).
// (verified R4; only change: f-branch reads xT contiguously instead of the
//  stride-16 gather of x)
// ---------------------------------------------------------------------------
__global__ __launch_bounds__(192) void embed_kernel(
    const float* __restrict__ x, const float* __restrict__ xT,
    const float* __restrict__ wT, const float* __restrict__ bT,
    const float* __restrict__ tokT, const float* __restrict__ posT,
    const float* __restrict__ nwT,
    const float* __restrict__ wF, const float* __restrict__ bF,
    const float* __restrict__ tokF, const float* __restrict__ posF,
    const float* __restrict__ nwF,
    float* __restrict__ res,
    unsigned short* __restrict__ hHi, unsigned short* __restrict__ hLo)
{
  const int t = threadIdx.x;
  int bx = blockIdx.x;
  const int is_f = bx >> 9;
  bx &= 511;
  const int p = bx & 15;
  const int bg = bx >> 4;          // 0..31, batches bg*4..bg*4+3
  const float* w    = is_f ? wF : wT;
  const float* bias = is_f ? bF : bT;
  const float* tok  = is_f ? tokF : tokT;
  const float* pos  = is_f ? posF : posT;
  const float* nw   = is_f ? nwF : nwT;
  const size_t sbase = is_f ? (size_t)NB*ROW : 0;

  __shared__ alignas(16) float xs[4*1792];
  __shared__ float lds_sq[5*192];
  __shared__ float lds_pt[5*16];
  __shared__ float lds_sc[5];

  for (int idx = t; idx < 4*1792; idx += 192) {
    int bb = idx / 1792;
    int r = idx - bb*1792;
    int b = bg*4 + bb;
    if (!is_f) {
      int c = r / 224;
      int rr = r - c*224;
      xs[idx] = x[((size_t)(b*8 + c)*224 + p*14)*16 + rr];
    } else {
      xs[idx] = xT[((size_t)b*16 + p)*1792 + r];   // contiguous (R7 fix)
    }
  }
  __syncthreads();

  float acc[4];
#pragma unroll
  for (int i = 0; i < 4; ++i) acc[i] = 0.f;
  const float4* wr = (const float4*)w + t*448;
  const float4* xv = (const float4*)xs;
  for (int k4 = 0; k4 < 448; ++k4) {
    float4 w4 = wr[k4];
#pragma unroll
    for (int bb = 0; bb < 4; ++bb) acc[bb] += dot4(xv[bb*448 + k4], w4);
  }
  float add = bias[t] + pos[p*DM + t];
  float v[4];
#pragma unroll
  for (int bb = 0; bb < 4; ++bb) {
    v[bb] = acc[bb] + add;
    lds_sq[bb*192 + t] = v[bb]*v[bb];
  }
  float v16 = tok[t] + pos[16*DM + t];
  lds_sq[4*192 + t] = v16*v16;
  __syncthreads();
  if (t < 80) {
    int r = t >> 4, j = t & 15;
    float s = 0.f;
#pragma unroll
    for (int k = 0; k < 12; ++k) s += lds_sq[r*192 + j + 16*k];
    lds_pt[t] = s;
  }
  __syncthreads();
  if (t < 5) {
    float s = 0.f;
#pragma unroll
    for (int j = 0; j < 16; ++j) s += lds_pt[t*16 + j];
    lds_sc[t] = rsqrtf(s*(1.0f/192.0f) + 1e-5f);
  }
  __syncthreads();
  float nwt = nw[t];
#pragma unroll
  for (int bb = 0; bb < 4; ++bb) {
    size_t base = sbase + (size_t)(bg*4 + bb)*ROW + p*DM + t;
    res[base] = v[bb];
    unsigned short h, l;
    split2(v[bb]*lds_sc[bb]*nwt, h, l);
    hHi[base] = h; hLo[base] = l;
  }
  if (p == 0) {
    float s16 = lds_sc[4];
#pragma unroll
    for (int bb = 0; bb < 4; ++bb) {
      size_t base = sbase + (size_t)(bg*4 + bb)*ROW + 16*DM + t;
      res[base] = v16;
      unsigned short h, l;
      split2(v16*s16*nwt, h, l);
      hHi[base] = h; hLo[base] = l;
    }
  }
}

// ---------------------------------------------------------------------------
// Split-bf16 MFMA GEMM (verified R4): C[n][m] = sum_k A[n][k]*B[m][k].
// Tile 64(n) x MT(m), K-step 32, 256 threads = 4 waves.
// ---------------------------------------------------------------------------
template<int MT>
__global__ __launch_bounds__(256) void gemm_mfma(
    const unsigned short* __restrict__ Ahi, const unsigned short* __restrict__ Alo, int lda,
    const unsigned short* __restrict__ BtHi, const unsigned short* __restrict__ BtLo,
    const unsigned short* __restrict__ BfHi, const unsigned short* __restrict__ BfLo,
    int ldb, int kchunk, float* __restrict__ C, int ldc, long ckstride)
{
  const int t = threadIdx.x;
  const int mt = blockIdx.x, nt = blockIdx.y, kz = blockIdx.z;
  __shared__ alignas(16) unsigned short sAh[64*40], sAl[64*40];
  __shared__ alignas(16) unsigned short sBh[MT*40], sBl[MT*40];

  const bool isT = (nt < 34);
  const unsigned short* aH = Ahi + (size_t)(nt*64)*lda + kz*kchunk;
  const unsigned short* aL = Alo + (size_t)(nt*64)*lda + kz*kchunk;
  const unsigned short* bH = (isT ? BtHi : BfHi) + (size_t)(mt*MT)*ldb + kz*kchunk;
  const unsigned short* bL = (isT ? BtLo : BfLo) + (size_t)(mt*MT)*ldb + kz*kchunk;

  const int wave = t >> 6, lane = t & 63;
  const int arow = wave*16 + (lane & 15);
  const int kb   = (lane >> 4) * 8;

  f32x4 acc[MT/16];
#pragma unroll
  for (int mb = 0; mb < MT/16; ++mb) acc[mb] = (f32x4){0.f, 0.f, 0.f, 0.f};

  const int srow = t >> 2, sseg = (t & 3) * 8;

  for (int kt = 0; kt < kchunk; kt += 32) {
    __syncthreads();
    *(uint4*)(sAh + srow*40 + sseg) = *(const uint4*)(aH + (size_t)srow*lda + kt + sseg);
    *(uint4*)(sAl + srow*40 + sseg) = *(const uint4*)(aL + (size_t)srow*lda + kt + sseg);
#pragma unroll
    for (int rep = 0; rep < MT/64; ++rep) {
      int r2 = rep*64 + srow;
      *(uint4*)(sBh + r2*40 + sseg) = *(const uint4*)(bH + (size_t)r2*ldb + kt + sseg);
      *(uint4*)(sBl + r2*40 + sseg) = *(const uint4*)(bL + (size_t)r2*ldb + kt + sseg);
    }
    __syncthreads();
    bf16x8 ah = *(const bf16x8*)(sAh + arow*40 + kb);
    bf16x8 al = *(const bf16x8*)(sAl + arow*40 + kb);
#pragma unroll
    for (int mb = 0; mb < MT/16; ++mb) {
      bf16x8 bh = *(const bf16x8*)(sBh + (mb*16 + (lane & 15))*40 + kb);
      bf16x8 bl = *(const bf16x8*)(sBl + (mb*16 + (lane & 15))*40 + kb);
      acc[mb] = __builtin_amdgcn_mfma_f32_16x16x32_bf16(al, bh, acc[mb], 0, 0, 0);
      acc[mb] = __builtin_amdgcn_mfma_f32_16x16x32_bf16(ah, bl, acc[mb], 0, 0, 0);
      acc[mb] = __builtin_amdgcn_mfma_f32_16x16x32_bf16(ah, bh, acc[mb], 0, 0, 0);
    }
  }

  float* Cb = C + (long)kz*ckstride
            + (size_t)(nt*64 + wave*16 + (lane >> 4)*4)*ldc + mt*MT + (lane & 15);
#pragma unroll
  for (int mb = 0; mb < MT/16; ++mb)
#pragma unroll
    for (int r = 0; r < 4; ++r)
      Cb[(size_t)r*ldc + mb*16] = acc[mb][r];
}

// ---------------------------------------------------------------------------
// Per-(s,b): conv+silu -> x_proj -> dt -> selective scan -> gate -> y hi/lo.
// grid 256, block 384 (thread = DI channel). (verified R4)
// ---------------------------------------------------------------------------
__global__ __launch_bounds__(384) void mid_kernel(
    const float* __restrict__ xzg,
    unsigned short* __restrict__ yHi, unsigned short* __restrict__ yLo,
    MambaW wt, MambaW wf, int layer)
{
  const int t = threadIdx.x;
  const int sb = blockIdx.x;
  const MambaW W = (sb >= NB) ? wf : wt;
  __shared__ alignas(16) float lds_xx[SEQ*388];
  __shared__ alignas(16) float lds_dbl[748];
  const size_t nb = (size_t)sb*SEQ;

  float xr[SEQ];
  {
    const float4 cw = ((const float4*)(W.conv_w + (size_t)layer*DI*4))[t];
    const float cb = W.conv_b[layer*DI + t];
    float p0 = 0.f, p1 = 0.f, p2 = 0.f;
#pragma unroll
    for (int l = 0; l < SEQ; ++l) {
      float xz = xzg[(nb + l)*768 + t];
      float v = cb + xz*cw.w + p0*cw.z + p1*cw.y + p2*cw.x;
      p2 = p1; p1 = p0; p0 = xz;
      v = v / (1.f + __expf(-v));
      xr[l] = v;
      lds_xx[l*388 + t] = v;
    }
  }
  __syncthreads();

  {
    const float* XP = W.x_proj + (size_t)layer*44*DI;
#pragma unroll
    for (int rep = 0; rep < 2; ++rep) {
      int o = t + rep*384;
      if (o < 748) {
        int l = o / 44, j = o - l*44;
        const float4* wr = (const float4*)(XP + j*DI);
        const float4* xv4 = (const float4*)lds_xx + l*97;
        float a = 0.f;
        for (int k4 = 0; k4 < 96; ++k4) a += dot4(xv4[k4], wr[k4]);
        lds_dbl[o] = a;
      }
    }
  }
  __syncthreads();

  {
    const int c = t;
    const float* dwr = W.dt_w + (size_t)layer*DI*12 + c*12;
    float w0[12];
#pragma unroll
    for (int r = 0; r < 12; ++r) w0[r] = dwr[r];
    const float dtb = W.dt_b[layer*DI + c];
    const float4* alr = (const float4*)(W.A_log + (size_t)layer*DI*16) + c*4;
    float Av[16];
#pragma unroll
    for (int q = 0; q < 4; ++q) {
      float4 a4 = alr[q];
      Av[q*4+0] = -__expf(a4.x); Av[q*4+1] = -__expf(a4.y);
      Av[q*4+2] = -__expf(a4.z); Av[q*4+3] = -__expf(a4.w);
    }
    const float Dp = W.D[layer*DI + c];
    float hst[16];
#pragma unroll
    for (int n = 0; n < 16; ++n) hst[n] = 0.f;
    for (int l = 0; l < SEQ; ++l) {
      float a = dtb;
#pragma unroll
      for (int r = 0; r < 12; ++r) a += lds_dbl[l*44 + r]*w0[r];
      float dt = (a > 20.f) ? a : log1pf(__expf(a));
      float xv = xr[l];
      const float4* dbv = (const float4*)(lds_dbl + l*44 + 12);
      float4 Bq[4], Cq[4];
      Bq[0]=dbv[0]; Bq[1]=dbv[1]; Bq[2]=dbv[2]; Bq[3]=dbv[3];
      Cq[0]=dbv[4]; Cq[1]=dbv[5]; Cq[2]=dbv[6]; Cq[3]=dbv[7];
      const float* Bs = (const float*)Bq;
      const float* Cs = (const float*)Cq;
      float y = 0.f;
      float dbx = dt * xv;
#pragma unroll
      for (int n = 0; n < 16; ++n) {
        float dA = __expf(dt * Av[n]);
        float hn = dA*hst[n] + dbx*Bs[n];
        hst[n] = hn;
        y += hn*Cs[n];
      }
      y += Dp * xv;
      float zv = xzg[(nb + l)*768 + DI + c];
      y *= zv / (1.f + __expf(-zv));
      unsigned short h, lo_;
      split2(y, h, lo_);
      size_t idx = (nb + l)*DI + c;
      yHi[idx] = h; yLo[idx] = lo_;
    }
  }
}

// ---------------------------------------------------------------------------
// Sum 2 K-split partials + residual + RMSNorm -> hbuf hi/lo (or final xfin).
// grid 256 (sb), block 192 (thread = d). (verified R4)
// ---------------------------------------------------------------------------
__global__ __launch_bounds__(192) void fuse_kernel(
    const float* __restrict__ part, float* __restrict__ res,
    unsigned short* __restrict__ hHi, unsigned short* __restrict__ hLo,
    float* __restrict__ xfin,
    const float* __restrict__ nwT, const float* __restrict__ nwF,
    int layer, int last)
{
  const int d = threadIdx.x;
  const int sb = blockIdx.x;
  const size_t nb = (size_t)sb*SEQ;
  __shared__ float sq[SEQ*192];
  __shared__ float pt[SEQ*8];
  __shared__ float sc[SEQ];

  float v[SEQ];
#pragma unroll
  for (int l = 0; l < SEQ; ++l) {
    size_t idx = (nb + l)*DM + d;
    float s = part[idx] + part[(size_t)N192 + idx];
    if (!last) {
      s += res[idx];
      res[idx] = s;
      v[l] = s;
      sq[l*192 + d] = s*s;
    } else {
      xfin[idx] = s;
    }
  }
  if (last) return;
  __syncthreads();
  if (d < 136) {
    int l = d >> 3, j = d & 7;
    float s = 0.f;
#pragma unroll
    for (int q = 0; q < 24; ++q) s += sq[l*192 + j + 8*q];
    pt[d] = s;
  }
  __syncthreads();
  if (d < SEQ) {
    float s = 0.f;
#pragma unroll
    for (int j = 0; j < 8; ++j) s += pt[d*8 + j];
    sc[d] = rsqrtf(s*(1.0f/192.0f) + 1e-5f);
  }
  __syncthreads();
  const float* nw = ((sb < NB) ? nwT : nwF) + (size_t)(layer + 1)*DM;
  float nwd = nw[d];
#pragma unroll
  for (int l = 0; l < SEQ; ++l) {
    unsigned short h, lo_;
    split2(v[l]*sc[l]*nwd, h, lo_);
    size_t idx = (nb + l)*DM + d;
    hHi[idx] = h; hLo[idx] = lo_;
  }
}

// ---------------------------------------------------------------------------
// Attention K/V GEMM (fp32 VALU, verified R3/R4). grid (8,17).
// ---------------------------------------------------------------------------
__global__ __launch_bounds__(256, 3) void gemm_kv(
    const float* __restrict__ A, int lda, int ktot,
    const float* __restrict__ Bt, const float* __restrict__ Bf, int ldb,
    const float* __restrict__ bias1, const float* __restrict__ bias2,
    float* __restrict__ C, int ldc)
{
  const int t  = threadIdx.x;
  const int mt = blockIdx.x, nt = blockIdx.y;
  __shared__ float As[32][132];
  __shared__ float Bs[32][100];

  int pass = mt >> 2, kv = (mt >> 1) & 1, half = mt & 1;
  const float* Bp = (pass ? Bf : Bt) + (size_t)(1+kv)*DM*DM + (size_t)(half*96)*ldb;
  const float* bp = (pass ? bias2 : bias1) + (1+kv)*DM + half*96;
  const float* Ap = A + (size_t)(nt*128)*lda;

  const int tn = t & 15, tm = t >> 4;
  float acc[8][6];
#pragma unroll
  for (int i = 0; i < 8; ++i)
#pragma unroll
    for (int j = 0; j < 6; ++j) acc[i][j] = 0.f;

  const int srow = t >> 1;
  const int skl  = (t & 1) * 16;

  for (int kt = 0; kt < ktot; kt += 32) {
    __syncthreads();
    {
      const float* ar = Ap + (size_t)srow*lda + kt + skl;
      float4 v0 = *(const float4*)(ar + 0);
      float4 v1 = *(const float4*)(ar + 4);
      float4 v2 = *(const float4*)(ar + 8);
      float4 v3 = *(const float4*)(ar + 12);
      As[skl+ 0][srow]=v0.x; As[skl+ 1][srow]=v0.y; As[skl+ 2][srow]=v0.z; As[skl+ 3][srow]=v0.w;
      As[skl+ 4][srow]=v1.x; As[skl+ 5][srow]=v1.y; As[skl+ 6][srow]=v1.z; As[skl+ 7][srow]=v1.w;
      As[skl+ 8][srow]=v2.x; As[skl+ 9][srow]=v2.y; As[skl+10][srow]=v2.z; As[skl+11][srow]=v2.w;
      As[skl+12][srow]=v3.x; As[skl+13][srow]=v3.y; As[skl+14][srow]=v3.z; As[skl+15][srow]=v3.w;
    }
    if (srow < 96) {
      const float* br = Bp + (size_t)srow*ldb + kt + skl;
      float4 v0 = *(const float4*)(br + 0);
      float4 v1 = *(const float4*)(br + 4);
      float4 v2 = *(const float4*)(br + 8);
      float4 v3 = *(const float4*)(br + 12);
      Bs[skl+ 0][srow]=v0.x; Bs[skl+ 1][srow]=v0.y; Bs[skl+ 2][srow]=v0.z; Bs[skl+ 3][srow]=v0.w;
      Bs[skl+ 4][srow]=v1.x; Bs[skl+ 5][srow]=v1.y; Bs[skl+ 6][srow]=v1.z; Bs[skl+ 7][srow]=v1.w;
      Bs[skl+ 8][srow]=v2.x; Bs[skl+ 9][srow]=v2.y; Bs[skl+10][srow]=v2.z; Bs[skl+11][srow]=v2.w;
      Bs[skl+12][srow]=v3.x; Bs[skl+13][srow]=v3.y; Bs[skl+14][srow]=v3.z; Bs[skl+15][srow]=v3.w;
    }
    __syncthreads();
#pragma unroll
    for (int kk = 0; kk < 32; ++kk) {
      float a[8], b[6];
      *(float4*)&a[0] = *(const float4*)&As[kk][tn*4];
      *(float4*)&a[4] = *(const float4*)&As[kk][64 + tn*4];
      *(float2*)&b[0] = *(const float2*)&Bs[kk][tm*6];
      *(float2*)&b[2] = *(const float2*)&Bs[kk][tm*6+2];
      *(float2*)&b[4] = *(const float2*)&Bs[kk][tm*6+4];
#pragma unroll
      for (int i = 0; i < 8; ++i)
#pragma unroll
        for (int j = 0; j < 6; ++j) acc[i][j] = fmaf(a[i], b[j], acc[i][j]);
    }
  }

  float* Cb = C + (size_t)(nt*128)*ldc + mt*96;
#pragma unroll
  for (int ni = 0; ni < 8; ++ni) {
    int n = (ni < 4) ? tn*4 + ni : 64 + tn*4 + (ni - 4);
    float* cr = Cb + (size_t)n*ldc;
#pragma unroll
    for (int j = 0; j < 6; ++j) cr[tm*6 + j] = acc[ni][j] + bp[tm*6 + j];
  }
}

// ---------------------------------------------------------------------------
// Attention core (query row 16 only) + MLP heads. grid 128 (b), block 192.
// (verified R4)
// ---------------------------------------------------------------------------
__global__ __launch_bounds__(192) void attn_core_kernel(
    const float* __restrict__ xfin, const float* __restrict__ kvg,
    const float* __restrict__ w1, const float* __restrict__ b1,
    const float* __restrict__ w2, const float* __restrict__ b2,
    const float* __restrict__ c1w, const float* __restrict__ c1b,
    const float* __restrict__ c2w, const float* __restrict__ c2b,
    const float* __restrict__ p1w, const float* __restrict__ p1b,
    const float* __restrict__ p2w, const float* __restrict__ p2b,
    float* __restrict__ out)
{
  const int d = threadIdx.x;
  const int b = blockIdx.x;
  __shared__ alignas(16) float lds_t16[DM];
  __shared__ alignas(16) float lds_q[DM];
  __shared__ alignas(16) float lds_o[DM];
  __shared__ alignas(16) float lds_t1[DM];
  __shared__ alignas(16) float lds_feat[DM];
  __shared__ alignas(16) float lds_hc[512];
  __shared__ alignas(16) float lds_hp[512];

  lds_t16[d] = xfin[((size_t)b*SEQ + 16)*DM + d];
  __syncthreads();

  for (int pass = 0; pass < 2; ++pass) {
    const float* wa = pass ? w2 : w1;
    const float* ba = pass ? b2 : b1;
    {
      const float* qsrc = pass ? lds_t1 : lds_t16;
      const float4* wr = (const float4*)wa + d*48;
      const float4* a4 = (const float4*)qsrc;
      float acc = ba[d];
      for (int k4 = 0; k4 < 48; ++k4) acc += dot4(a4[k4], wr[k4]);
      lds_q[d] = acc;
    }
    __syncthreads();
    {
      int h = d / 24;
      float4 q0 = *(const float4*)&lds_q[h*24];
      float4 q1 = *(const float4*)&lds_q[h*24+4];
      float4 q2 = *(const float4*)&lds_q[h*24+8];
      float4 q3 = *(const float4*)&lds_q[h*24+12];
      float4 q4 = *(const float4*)&lds_q[h*24+16];
      float4 q5 = *(const float4*)&lds_q[h*24+20];
      float scs[SEQ];
      float mx = -1e30f;
#pragma unroll
      for (int lk = 0; lk < SEQ; ++lk) {
        const float4* kr = (const float4*)(kvg + ((size_t)b*SEQ + lk)*768 + pass*384 + h*24);
        float s_ = dot4(q0,kr[0]) + dot4(q1,kr[1]) + dot4(q2,kr[2])
                 + dot4(q3,kr[3]) + dot4(q4,kr[4]) + dot4(q5,kr[5]);
        s_ *= 0.20412414523193154f;
        scs[lk] = s_;
        mx = fmaxf(mx, s_);
      }
      float den = 0.f;
#pragma unroll
      for (int lk = 0; lk < SEQ; ++lk) { float e = __expf(scs[lk]-mx); scs[lk]=e; den += e; }
      float inv = 1.f/den;
      float o = 0.f;
#pragma unroll
      for (int lk = 0; lk < SEQ; ++lk)
        o += scs[lk] * kvg[((size_t)b*SEQ + lk)*768 + pass*384 + DM + d];
      lds_o[d] = o*inv;
    }
    __syncthreads();
    {
      const float4* wr = (const float4*)(wa + 3*DM*DM) + d*48;
      const float4* a4 = (const float4*)lds_o;
      float acc = ba[3*DM + d];
      for (int k4 = 0; k4 < 48; ++k4) acc += dot4(a4[k4], wr[k4]);
      if (pass == 0) lds_t1[d] = acc;
      else lds_feat[d] = acc + lds_t16[d];
    }
    __syncthreads();
  }

  for (int u = d; u < 512; u += 192) {
    const float4* wc = (const float4*)c1w + u*48;
    const float4* wp = (const float4*)p1w + u*48;
    const float4* fv = (const float4*)lds_feat;
    float a1 = c1b[u], a2 = p1b[u];
    for (int k4 = 0; k4 < 48; ++k4) {
      float4 f4 = fv[k4];
      a1 += dot4(f4, wc[k4]);
      a2 += dot4(f4, wp[k4]);
    }
    lds_hc[u] = fmaxf(a1, 0.f);
    lds_hp[u] = fmaxf(a2, 0.f);
  }
  __syncthreads();
  if (d < 10) {
    const float4* wr = (const float4*)c2w + d*128;
    float acc = c2b[d];
    for (int k4 = 0; k4 < 128; ++k4) acc += dot4(((const float4*)lds_hc)[k4], wr[k4]);
    out[b*10 + d] = acc;
  }
  if (d >= 64 && d < 67) {
    int j = d - 64;
    const float4* wr = (const float4*)p2w + j*128;
    float acc = p2b[j];
    for (int k4 = 0; k4 < 128; ++k4) acc += dot4(((const float4*)lds_hp)[k4], wr[k4]);
    out[1280 + b*3 + j] = acc;
  }
}

extern "C" void kernel_launch(void* const* d_in, const int* in_sizes, int n_in,
                              void* d_out, int out_size, void* d_ws, size_t ws_size,
                              hipStream_t stream)
{
  (void)in_sizes; (void)n_in; (void)out_size; (void)ws_size;
  const float* x    = (const float*)d_in[0];
  const float* tpw  = (const float*)d_in[1];
  const float* tpb  = (const float*)d_in[2];
  const float* fpw  = (const float*)d_in[3];
  const float* fpb  = (const float*)d_in[4];
  const float* ttok = (const float*)d_in[5];
  const float* ftok = (const float*)d_in[6];
  const float* tpos = (const float*)d_in[7];
  const float* fpos = (const float*)d_in[8];
  MambaW wt { (const float*)d_in[9],  (const float*)d_in[10], (const float*)d_in[11],
              (const float*)d_in[12], (const float*)d_in[13], (const float*)d_in[14],
              (const float*)d_in[15], (const float*)d_in[16], (const float*)d_in[17],
              (const float*)d_in[18] };
  MambaW wf { (const float*)d_in[19], (const float*)d_in[20], (const float*)d_in[21],
              (const float*)d_in[22], (const float*)d_in[23], (const float*)d_in[24],
              (const float*)d_in[25], (const float*)d_in[26], (const float*)d_in[27],
              (const float*)d_in[28] };
  const float* attw  = (const float*)d_in[29];
  const float* attb  = (const float*)d_in[30];
  const float* attw2 = (const float*)d_in[31];
  const float* attb2 = (const float*)d_in[32];
  const float* c1w = (const float*)d_in[33];
  const float* c1b = (const float*)d_in[34];
  const float* c2w = (const float*)d_in[35];
  const float* c2b = (const float*)d_in[36];
  const float* p1w = (const float*)d_in[37];
  const float* p1b = (const float*)d_in[38];
  const float* p2w = (const float*)d_in[39];
  const float* p2b = (const float*)d_in[40];

  // ws layout byte-identical to R4 (proven 55.31 MiB). xT (3.67M floats)
  // aliases the xzg+part region (6*N192 = 5.01M floats), dead until gemm_in.
  float* ws = (float*)d_ws;
  size_t off = 0;
  float* res  = ws + off; off += (size_t)N192;
  float* xfin = ws + off; off += (size_t)N192;
  float* xzg  = ws + off; off += (size_t)4*N192;       // NROWS x 768
  float* part = ws + off; off += (size_t)2*N192;       // 2 K-split partials (also kvg)
  unsigned short* hHi = (unsigned short*)(ws + off); off += (size_t)N192/2;
  unsigned short* hLo = (unsigned short*)(ws + off); off += (size_t)N192/2;
  unsigned short* yHi = (unsigned short*)(ws + off); off += (size_t)N192;   // NROWS x 384
  unsigned short* yLo = (unsigned short*)(ws + off); off += (size_t)N192;
  unsigned short* ipHi = (unsigned short*)(ws + off); off += (size_t)C1IP; // 2 streams
  unsigned short* ipLo = (unsigned short*)(ws + off); off += (size_t)C1IP;
  unsigned short* opHi = (unsigned short*)(ws + off); off += (size_t)C2OP;
  unsigned short* opLo = (unsigned short*)(ws + off); off += (size_t)C2OP;
  float* kvg = part;
  float* xT  = xzg;   // [128][16][1792] fp32, dead before first gemm_in

  decomp_kernel<<<dim3(512, 2), 256, 0, stream>>>(wt.in_proj, wf.in_proj,
                                                  ipHi, ipLo, C1IP/4);
  decomp_kernel<<<dim3(512, 2), 256, 0, stream>>>(wt.out_proj, wf.out_proj,
                                                  opHi, opLo, C2OP/4);
  transpose_f_kernel<<<1024, 256, 0, stream>>>(x, xT);
  embed_kernel<<<1024, 192, 0, stream>>>(x, xT,
      tpw, tpb, ttok, tpos, wt.norm_w,
      fpw, fpb, ftok, fpos, wf.norm_w,
      res, hHi, hLo);

  for (int i = 0; i < DEPTH; ++i) {
    const size_t ipo = (size_t)i*2*DI*DM;
    const size_t opo = (size_t)i*DM*DI;
    gemm_mfma<128><<<dim3(6, 68, 1), 256, 0, stream>>>(
        hHi, hLo, DM,
        ipHi + ipo, ipLo + ipo, ipHi + C1IP + ipo, ipLo + C1IP + ipo,
        DM, DM /*kchunk=192*/, xzg, 768, 0);
    mid_kernel<<<256, 384, 0, stream>>>(xzg, yHi, yLo, wt, wf, i);
    gemm_mfma<64><<<dim3(3, 68, 2), 256, 0, stream>>>(
        yHi, yLo, DI,
        opHi + opo, opLo + opo, opHi + C2OP + opo, opLo + C2OP + opo,
        DI, 192, part, DM, (long)N192);
    fuse_kernel<<<256, 192, 0, stream>>>(part, res, hHi, hLo, xfin,
        wt.norm_w, wf.norm_w, i, (i == DEPTH-1) ? 1 : 0);
  }

  gemm_kv<<<dim3(8, 17), 256, 0, stream>>>(
      xfin + (size_t)NB*ROW, DM, DM,
      attw, attw2, DM, attb, attb2, kvg, 768);
  attn_core_kernel<<<128, 192, 0, stream>>>(xfin, kvg,
      attw, attb, attw2, attb2,
      c1w, c1b, c2w, c2b, p1w, p1b, p2w, p2b, (float*)d_out);
}